// Round 14
// baseline (237.188 us; speedup 1.0000x reference)
//
#include <hip/hip_runtime.h>
#include <hip/hip_bf16.h>

#define T_TOKENS 4096
#define HID 1024
#define INTER 2048
#define NEXP 8
#define TOPK 2
#define RTOT (T_TOKENS * TOPK) /* 8192 */
#define BMT 128
#define BN 128
#define MAXT (RTOT / BMT + NEXP) /* 72 */

typedef __attribute__((ext_vector_type(8))) short bf16x8;
typedef __attribute__((ext_vector_type(4))) float f32x4;

typedef __attribute__((address_space(1))) const unsigned int gu32;
typedef __attribute__((address_space(3))) unsigned int lu32;

__device__ __forceinline__ void gl16(const void* g, void* l) {
  __builtin_amdgcn_global_load_lds((gu32*)g, (lu32*)l, 16, 0, 0);
}

__device__ __forceinline__ unsigned f2bf(float f) {
  union { float f; unsigned u; } v; v.f = f;
  unsigned u = v.u;
  return (u + 0x7FFFu + ((u >> 16) & 1u)) >> 16;
}

// packed RNE f32x2 -> bf16x2 (single instruction; src0 -> low half)
__device__ __forceinline__ unsigned cvtpk(float lo, float hi) {
  unsigned r;
  asm("v_cvt_pk_bf16_f32 %0, %1, %2" : "=v"(r) : "v"(lo), "v"(hi));
  return r;
}

__device__ __forceinline__ float bf2f(unsigned short s) {
  union { unsigned u; float f; } v; v.u = ((unsigned)s) << 16;
  return v.f;
}

// old-style swizzle for the fallback kernels ([row][64bf16], 128B rows)
__device__ __forceinline__ int swz(int row, int kb) {
  return row * 128 + (kb ^ ((row & 7) << 4));
}

__device__ __forceinline__ void phase_barrier() {
  asm volatile("" ::: "memory");
  __builtin_amdgcn_s_barrier();
  asm volatile("" ::: "memory");
}

// prep LDS swizzle key: bank-conflict-free column reads (2-way max).
__device__ __forceinline__ int psig(int kap) { return kap ^ ((kap & 1) << 2); }

// ---- routing for fallback path (standalone) ----
__global__ __launch_bounds__(1024)
void k_routing(const float* __restrict__ logits, int* ntiles,
               int* te2, int* tr02, int* tcnt2,
               float* pw, int* rows, float* rw, int* slotOf) {
  __shared__ int cnt[NEXP];
  __shared__ int cur[NEXP];
  const int tid = threadIdx.x;
  if (tid < NEXP) cnt[tid] = 0;
  __syncthreads();
#pragma unroll
  for (int j = 0; j < 4; ++j) {
    int t = j * 1024 + tid;
    float l[NEXP];
#pragma unroll
    for (int i = 0; i < NEXP; ++i) l[i] = logits[t * NEXP + i];
    int i0 = 0; float b0 = l[0];
#pragma unroll
    for (int i = 1; i < NEXP; ++i) if (l[i] > b0) { b0 = l[i]; i0 = i; }
    int i1 = -1; float b1 = -1e30f;
#pragma unroll
    for (int i = 0; i < NEXP; ++i) if (i != i0 && l[i] > b1) { b1 = l[i]; i1 = i; }
    float e = __expf(b1 - b0);
    float w0 = 1.f / (1.f + e);
    float w1 = e / (1.f + e);
    pw[2 * t] = w0; pw[2 * t + 1] = w1;
#pragma unroll
    for (int ex = 0; ex < NEXP; ++ex) {
      int c = __popcll(__ballot(i0 == ex)) + __popcll(__ballot(i1 == ex));
      if ((tid & 63) == 0 && c) atomicAdd(&cnt[ex], c);
    }
  }
  __syncthreads();
  if (tid == 0) {
    int off = 0, nm = 0;
    for (int e = 0; e < NEXP; ++e) {
      int c = cnt[e];
      cur[e] = off;
      for (int m0 = 0; m0 < c; m0 += BMT) {
        te2[nm] = e; tr02[nm] = off + m0; tcnt2[nm] = min(BMT, c - m0); ++nm;
      }
      off += c;
    }
    ntiles[1] = nm;
  }
  __syncthreads();
#pragma unroll
  for (int j = 0; j < 4; ++j) {
    int t = j * 1024 + tid;
    float l[NEXP];
#pragma unroll
    for (int i = 0; i < NEXP; ++i) l[i] = logits[t * NEXP + i];
    int i0 = 0; float b0 = l[0];
#pragma unroll
    for (int i = 1; i < NEXP; ++i) if (l[i] > b0) { b0 = l[i]; i0 = i; }
    int i1 = -1; float b1 = -1e30f;
#pragma unroll
    for (int i = 0; i < NEXP; ++i) if (i != i0 && l[i] > b1) { b1 = l[i]; i1 = i; }
    float e = __expf(b1 - b0);
    float ww[2] = {1.f / (1.f + e), e / (1.f + e)};
    int ee[2] = {i0, i1};
#pragma unroll
    for (int k = 0; k < TOPK; ++k) {
      int s = atomicAdd(&cur[ee[k]], 1);
      rows[s] = t;
      rw[s] = ww[k];
      slotOf[2 * t + k] = s;
    }
  }
}

// ---- prepass + routing, ONE launch (5121 blocks x 256 thr):
//  block 0:            routing (top2 + tile list + scatter)
//  blocks [1,1025):    X f32 -> bf16
//  blocks [1025,5121): W0/W1 f32 -> bf16 tiles [E][16][16][128n][32k]
__global__ __launch_bounds__(256)
void k_prep1r(const float* __restrict__ X, unsigned short* __restrict__ Xb,
              const float* __restrict__ W0, const float* __restrict__ W1,
              unsigned short* __restrict__ T0, unsigned short* __restrict__ T1,
              const float* __restrict__ logits, int* ntiles,
              int* te2, int* tr02, int* tcnt2,
              float* pw, int* rows, float* rw, int* slotOf) {
  int bid = blockIdx.x;
  const int tid = threadIdx.x;

  if (bid == 0) {
    // ---- routing: 256 threads x 16 tokens ----
    __shared__ int cnt[NEXP];
    __shared__ int cur[NEXP];
    if (tid < NEXP) cnt[tid] = 0;
    __syncthreads();
#pragma unroll
    for (int j = 0; j < 16; ++j) {
      int t = j * 256 + tid;
      float l[NEXP];
#pragma unroll
      for (int i = 0; i < NEXP; ++i) l[i] = logits[t * NEXP + i];
      int i0 = 0; float b0 = l[0];
#pragma unroll
      for (int i = 1; i < NEXP; ++i) if (l[i] > b0) { b0 = l[i]; i0 = i; }
      int i1 = -1; float b1 = -1e30f;
#pragma unroll
      for (int i = 0; i < NEXP; ++i) if (i != i0 && l[i] > b1) { b1 = l[i]; i1 = i; }
      float e = __expf(b1 - b0);
      float w0 = 1.f / (1.f + e);
      pw[2 * t] = w0; pw[2 * t + 1] = 1.f - w0;
#pragma unroll
      for (int ex = 0; ex < NEXP; ++ex) {
        int c = __popcll(__ballot(i0 == ex)) + __popcll(__ballot(i1 == ex));
        if ((tid & 63) == 0 && c) atomicAdd(&cnt[ex], c);
      }
    }
    __syncthreads();
    if (tid == 0) {
      int off = 0, nm = 0;
      for (int e = 0; e < NEXP; ++e) {
        int c = cnt[e];
        cur[e] = off;
        for (int m0 = 0; m0 < c; m0 += BMT) {
          te2[nm] = e; tr02[nm] = off + m0; tcnt2[nm] = min(BMT, c - m0); ++nm;
        }
        off += c;
      }
      ntiles[1] = nm;
    }
    __syncthreads();
    // scatter pass (recompute top2 -> low VGPR)
#pragma unroll
    for (int j = 0; j < 16; ++j) {
      int t = j * 256 + tid;
      float l[NEXP];
#pragma unroll
      for (int i = 0; i < NEXP; ++i) l[i] = logits[t * NEXP + i];
      int i0 = 0; float b0 = l[0];
#pragma unroll
      for (int i = 1; i < NEXP; ++i) if (l[i] > b0) { b0 = l[i]; i0 = i; }
      int i1 = -1; float b1 = -1e30f;
#pragma unroll
      for (int i = 0; i < NEXP; ++i) if (i != i0 && l[i] > b1) { b1 = l[i]; i1 = i; }
      float e = __expf(b1 - b0);
      float ww0 = 1.f / (1.f + e);
      int ee[2] = {i0, i1};
      float ww[2] = {ww0, 1.f - ww0};
#pragma unroll
      for (int k = 0; k < TOPK; ++k) {
        int s = atomicAdd(&cur[ee[k]], 1);
        rows[s] = t;
        rw[s] = ww[k];
        slotOf[2 * t + k] = s;
      }
    }
    return;
  }

  if (bid < 1025) {
    int base = (bid - 1) * 1024 + tid;
#pragma unroll
    for (int j = 0; j < 4; ++j) {
      int i = base + j * 256;
      float4 v = *(const float4*)(X + (size_t)i * 4);
      uint2 p;
      p.x = cvtpk(v.x, v.y);
      p.y = cvtpk(v.z, v.w);
      *(uint2*)(Xb + (size_t)i * 4) = p;
    }
    return;
  }
  bid -= 1025;
  const int w = bid >> 11;     // 0:W0 1:W1
  const int r = bid & 2047;
  const float* W = (w == 0) ? W0 : W1;
  unsigned short* T = (w == 0) ? T0 : T1;
  // nt fastest: 16 consecutive blocks cover full 2048-col row stripes
  const int nt = r & 15, kt = (r >> 4) & 15, e = r >> 8;
  __shared__ float ls[64 * 128];  // 32KB, conflict-free swizzle (psig)
  const float* src = W + (size_t)e * HID * INTER + (size_t)(kt * 64) * INTER + nt * 128;
#pragma unroll
  for (int t = 0; t < 8; ++t) {
    int u = t * 256 + tid;
    int k = u >> 5, n4 = u & 31;
    float4 v = *(const float4*)(src + (size_t)k * INTER + n4 * 4);
    *(float4*)(ls + k * 128 + ((n4 ^ psig(k >> 3)) << 2)) = v;
  }
  __syncthreads();
  unsigned short* dst = T + (((size_t)e * 16 + nt) * 16 + kt) * 8192;
#pragma unroll
  for (int t = 0; t < 4; ++t) {
    int v = t * 256 + tid;                       // uint4 index in output tile
    int kt2 = v >> 9, n = (v >> 2) & 127, sw = v & 3;
    int kc = kt2 * 4 + (sw ^ ((n >> 1) & 3));    // logical 8-k chunk
    const float* col = ls + (size_t)(kc * 8) * 128 +
                       (((n >> 2) ^ psig(kc)) << 2) + (n & 3);
    uint4 q;
    q.x = cvtpk(col[0 * 128], col[1 * 128]);
    q.y = cvtpk(col[2 * 128], col[3 * 128]);
    q.z = cvtpk(col[4 * 128], col[5 * 128]);
    q.w = cvtpk(col[6 * 128], col[7 * 128]);
    *(uint4*)(dst + (size_t)v * 8) = q;
  }
}

// ======== GEMM1 + WO-prep merged launch (interleaved dispatch) ========
// ty<144: even -> gemm tile ty/2, odd -> WO chunk ty/2
// ty>=144: WO chunk 72 + (ty-144)
__global__ __launch_bounds__(512, 4)
void k_gemm1w(const unsigned short* __restrict__ Xb,
              const unsigned short* __restrict__ WT0,
              const unsigned short* __restrict__ WT1,
              const float* __restrict__ WO,
              unsigned short* __restrict__ WTo,
              const int* __restrict__ ntiles, const int* __restrict__ te2,
              const int* __restrict__ tr02, const int* __restrict__ tcnt2,
              const int* __restrict__ rows,
              unsigned short* __restrict__ act) {
  const int tyr = blockIdx.y;
  const int nt = blockIdx.x;
  const int tid = threadIdx.x;
  __shared__ __align__(16) unsigned char sm[49152];

  const bool isWO = (tyr < 144) ? ((tyr & 1) != 0) : true;
  if (isWO) {
    // ---- WO prep block: [E][8][32][128n][32k] tiled bf16, nt-fastest ----
    const int wq = (tyr < 144) ? (tyr >> 1) : (72 + (tyr - 144));  // 0..127
    const int r = wq * 16 + nt;   // 0..2047
    const int ntt = r & 7, kt = (r >> 3) & 31, e = r >> 8;
    float* ls = (float*)sm;  // 32KB
    const float* src = WO + (size_t)e * INTER * HID + (size_t)(kt * 64) * HID + ntt * 128;
#pragma unroll
    for (int t = 0; t < 4; ++t) {
      int u = t * 512 + tid;               // 0..2047 float4 units
      int k = u >> 5, n4 = u & 31;
      float4 v = *(const float4*)(src + (size_t)k * HID + n4 * 4);
      *(float4*)(ls + k * 128 + ((n4 ^ psig(k >> 3)) << 2)) = v;
    }
    __syncthreads();
    unsigned short* dst = WTo + (((size_t)e * 8 + ntt) * 32 + kt) * 8192;
#pragma unroll
    for (int t = 0; t < 2; ++t) {
      int v = t * 512 + tid;               // 0..1023 uint4 units
      int kt2 = v >> 9, n = (v >> 2) & 127, sw = v & 3;
      int kc = kt2 * 4 + (sw ^ ((n >> 1) & 3));
      const float* col = ls + (size_t)(kc * 8) * 128 +
                         (((n >> 2) ^ psig(kc)) << 2) + (n & 3);
      uint4 q;
      q.x = cvtpk(col[0 * 128], col[1 * 128]);
      q.y = cvtpk(col[2 * 128], col[3 * 128]);
      q.z = cvtpk(col[4 * 128], col[5 * 128]);
      q.w = cvtpk(col[6 * 128], col[7 * 128]);
      *(uint4*)(dst + (size_t)v * 8) = q;
    }
    return;
  }

  const int ty = tyr >> 1;
  if (ty >= ntiles[1]) return;
  const int e = te2[ty], row0 = tr02[ty], mcnt = tcnt2[ty];
  const int n0 = nt * BN;
  const int lane = tid & 63, wv = tid >> 6;
  const int mh = wv >> 2, nq = wv & 3;  // wave out: 64m x 32n per B
  const int l15 = lane & 15, sl = lane >> 4;

  const int am = tid >> 2;
  const int atok = rows[row0 + (am < mcnt ? am : mcnt - 1)];
  const int askc = ((tid & 3) ^ ((tid >> 3) & 3)) * 8;  // shorts
  const unsigned short* B0t = WT0 + ((size_t)e * 16 + nt) * 32 * 4096;
  const unsigned short* B1t = WT1 + ((size_t)e * 16 + nt) * 32 * 4096;

  int aoff[4], boff[2];
#pragma unroll
  for (int f = 0; f < 4; ++f) {
    int m = mh * 64 + f * 16 + l15;
    aoff[f] = m * 64 + ((sl ^ ((m >> 1) & 3)) << 4);
  }
#pragma unroll
  for (int g = 0; g < 2; ++g) {
    int n = nq * 32 + g * 16 + l15;
    boff[g] = n * 64 + ((sl ^ ((n >> 1) & 3)) << 4);
  }

  f32x4 acc0[4][2], acc1[4][2];
  const f32x4 zz = {0.f, 0.f, 0.f, 0.f};
#pragma unroll
  for (int f = 0; f < 4; ++f)
#pragma unroll
    for (int g = 0; g < 2; ++g) { acc0[f][g] = zz; acc1[f][g] = zz; }

  const int NT_K = HID / 32;  // 32

  gl16(Xb + (size_t)atok * HID + askc, sm + tid * 16);
  gl16(B0t + (size_t)tid * 8, sm + 8192 + tid * 16);
  gl16(B1t + (size_t)tid * 8, sm + 16384 + tid * 16);

  for (int t = 0; t < NT_K; ++t) {
    unsigned char* cur = sm + (t & 1) * 24576;
    unsigned char* nxt = sm + ((t + 1) & 1) * 24576;
    const int tn = (t + 1 < NT_K) ? (t + 1) : (NT_K - 1);

    gl16(Xb + (size_t)atok * HID + tn * 32 + askc, nxt + tid * 16);
    gl16(B0t + (size_t)tn * 4096 + tid * 8, nxt + 8192 + tid * 16);
    gl16(B1t + (size_t)tn * 4096 + tid * 8, nxt + 16384 + tid * 16);
    asm volatile("s_waitcnt vmcnt(3)" ::: "memory");
    __builtin_amdgcn_sched_barrier(0);
    phase_barrier();

    bf16x8 aA[4], b0q[2], b1q[2];
#pragma unroll
    for (int g = 0; g < 2; ++g) {
      b0q[g] = *(const bf16x8*)(cur + 8192 + boff[g]);
      b1q[g] = *(const bf16x8*)(cur + 16384 + boff[g]);
    }
#pragma unroll
    for (int f = 0; f < 4; ++f) aA[f] = *(const bf16x8*)(cur + aoff[f]);
    __builtin_amdgcn_s_setprio(1);
#pragma unroll
    for (int f = 0; f < 4; ++f)
#pragma unroll
      for (int g = 0; g < 2; ++g) {
        acc0[f][g] = __builtin_amdgcn_mfma_f32_16x16x32_bf16(aA[f], b0q[g], acc0[f][g], 0, 0, 0);
        acc1[f][g] = __builtin_amdgcn_mfma_f32_16x16x32_bf16(aA[f], b1q[g], acc1[f][g], 0, 0, 0);
      }
    __builtin_amdgcn_s_setprio(0);
    phase_barrier();
  }

#pragma unroll
  for (int f = 0; f < 4; ++f) {
#pragma unroll
    for (int r = 0; r < 4; ++r) {
      int m = mh * 64 + f * 16 + sl * 4 + r;
      if (m >= mcnt) continue;
      size_t base = (size_t)(row0 + m) * INTER + n0 + nq * 32 + l15;
#pragma unroll
      for (int g = 0; g < 2; ++g) {
        float h0 = acc0[f][g][r];
        float h1 = acc1[f][g][r];
        float s = h0 / (1.f + __expf(-h0));
        act[base + g * 16] = (unsigned short)f2bf(s * h1);
      }
    }
  }
}

// ======== GEMM2: 128x128, 4 waves, BK=32, dbuf 32KB ========
// y[slot] = act@WO (bf16, unweighted)
__global__ __launch_bounds__(256, 4)
void k_gemm2n(const unsigned short* __restrict__ act,
              const unsigned short* __restrict__ WTo,
              const int* __restrict__ ntiles, const int* __restrict__ te2,
              const int* __restrict__ tr02, const int* __restrict__ tcnt2,
              unsigned short* __restrict__ y) {
  const int ty = blockIdx.y;
  if (ty >= ntiles[1]) return;
  const int e = te2[ty], row0 = tr02[ty], mcnt = tcnt2[ty];
  const int nt = blockIdx.x, n0 = nt * BN;
  const int tid = threadIdx.x, lane = tid & 63, wv = tid >> 6;
  const int wr = wv >> 1, wc = wv & 1;  // wave out 64x64
  const int l15 = lane & 15, sl = lane >> 4;

  // 2 x (A 8KB | B 8KB)
  __shared__ __align__(16) unsigned char sm[32768];

  const int am0 = tid >> 2, am1 = 64 + (tid >> 2);
  const int ar0 = row0 + (am0 < mcnt ? am0 : mcnt - 1);
  const int ar1 = row0 + (am1 < mcnt ? am1 : mcnt - 1);
  const int askc = ((tid & 3) ^ ((tid >> 3) & 3)) * 8;
  const unsigned short* Bt = WTo + ((size_t)e * 8 + nt) * 64 * 4096;

  int aoff[4], boff[4];
#pragma unroll
  for (int f = 0; f < 4; ++f) {
    int m = wr * 64 + f * 16 + l15;
    aoff[f] = m * 64 + ((sl ^ ((m >> 1) & 3)) << 4);
    int n = wc * 64 + f * 16 + l15;
    boff[f] = n * 64 + ((sl ^ ((n >> 1) & 3)) << 4);
  }

  f32x4 acc[4][4];
  const f32x4 zz = {0.f, 0.f, 0.f, 0.f};
#pragma unroll
  for (int i = 0; i < 4; ++i)
#pragma unroll
    for (int j = 0; j < 4; ++j) acc[i][j] = zz;

  const int NT_K = INTER / 32;  // 64

  gl16(act + (size_t)ar0 * INTER + askc, sm + tid * 16);
  gl16(act + (size_t)ar1 * INTER + askc, sm + (256 + tid) * 16);
  gl16(Bt + (size_t)tid * 8, sm + 8192 + tid * 16);
  gl16(Bt + (size_t)(256 + tid) * 8, sm + 8192 + (256 + tid) * 16);

  for (int t = 0; t < NT_K; ++t) {
    unsigned char* cur = sm + (t & 1) * 16384;
    unsigned char* nxt = sm + ((t + 1) & 1) * 16384;
    const int tn = (t + 1 < NT_K) ? (t + 1) : (NT_K - 1);

    gl16(act + (size_t)ar0 * INTER + tn * 32 + askc, nxt + tid * 16);
    gl16(act + (size_t)ar1 * INTER + tn * 32 + askc, nxt + (256 + tid) * 16);
    gl16(Bt + (size_t)tn * 4096 + tid * 8, nxt + 8192 + tid * 16);
    gl16(Bt + ((size_t)tn * 4096 + 2048) + tid * 8, nxt + 8192 + (256 + tid) * 16);
    asm volatile("s_waitcnt vmcnt(4)" ::: "memory");
    __builtin_amdgcn_sched_barrier(0);
    phase_barrier();

    bf16x8 af[4], bb[4];
#pragma unroll
    for (int f = 0; f < 4; ++f) {
      af[f] = *(const bf16x8*)(cur + aoff[f]);
      bb[f] = *(const bf16x8*)(cur + 8192 + boff[f]);
    }
    __builtin_amdgcn_s_setprio(1);
#pragma unroll
    for (int mf = 0; mf < 4; ++mf)
#pragma unroll
      for (int nf = 0; nf < 4; ++nf)
        acc[mf][nf] = __builtin_amdgcn_mfma_f32_16x16x32_bf16(af[mf], bb[nf], acc[mf][nf], 0, 0, 0);
    __builtin_amdgcn_s_setprio(0);
    phase_barrier();
  }

#pragma unroll
  for (int mf = 0; mf < 4; ++mf) {
#pragma unroll
    for (int r = 0; r < 4; ++r) {
      int m = wr * 64 + mf * 16 + sl * 4 + r;
      if (m >= mcnt) continue;
      unsigned short* yp = y + (size_t)(row0 + m) * HID + n0 + wc * 64 + l15;
#pragma unroll
      for (int nf = 0; nf < 4; ++nf)
        yp[nf * 16] = (unsigned short)f2bf(acc[mf][nf][r]);
    }
  }
}

// ---------------- combine: out[t] = w0*y[s0] + w1*y[s1] ----------------
__global__ void k_combine(const unsigned short* __restrict__ y,
                          const float* __restrict__ pw,
                          const int* __restrict__ slotOf,
                          float* __restrict__ out) {
  int idx = blockIdx.x * blockDim.x + threadIdx.x;
  int t = idx >> 7, hc = (idx & 127) * 8;
  int s0 = slotOf[2 * t], s1 = slotOf[2 * t + 1];
  float w0 = pw[2 * t], w1 = pw[2 * t + 1];
  uint4 a = *(const uint4*)(y + (size_t)s0 * HID + hc);
  uint4 b = *(const uint4*)(y + (size_t)s1 * HID + hc);
  float o[8];
  const unsigned* ap = (const unsigned*)&a;
  const unsigned* bp = (const unsigned*)&b;
#pragma unroll
  for (int i = 0; i < 4; ++i) {
    o[2 * i]     = w0 * bf2f((unsigned short)(ap[i] & 0xFFFF)) + w1 * bf2f((unsigned short)(bp[i] & 0xFFFF));
    o[2 * i + 1] = w0 * bf2f((unsigned short)(ap[i] >> 16))    + w1 * bf2f((unsigned short)(bp[i] >> 16));
  }
  float* op = out + (size_t)t * HID + hc;
  *(float4*)op = make_float4(o[0], o[1], o[2], o[3]);
  *(float4*)(op + 4) = make_float4(o[4], o[5], o[6], o[7]);
}

// ================= fallback (f32-direct, 128-tiles) if ws too small =================
__global__ __launch_bounds__(256, 2)
void k_gemm1_fb(const float* __restrict__ X, const float* __restrict__ W0,
                const float* __restrict__ W1, const int* __restrict__ ntiles,
                const int* __restrict__ te2, const int* __restrict__ tr02,
                const int* __restrict__ tcnt2, const int* __restrict__ rows,
                unsigned short* __restrict__ act) {
  const int ty = blockIdx.y;
  if (ty >= ntiles[1]) return;
  const int e = te2[ty], row0 = tr02[ty], mcnt = tcnt2[ty];
  const int n0 = blockIdx.x * BN;
  const int tid = threadIdx.x;
  const int lane = tid & 63, wv = tid >> 6;
  const int wr = wv >> 1, wc = wv & 1;

  __shared__ unsigned char smf[49152];
  unsigned char* As = smf;
  unsigned char* B0s = smf + 16384;
  unsigned char* B1s = smf + 32768;

  int atok[8];
#pragma unroll
  for (int j = 0; j < 8; ++j) {
    int m = (j * 256 + tid) >> 4;
    atok[j] = (m < mcnt) ? rows[row0 + m] : -1;
  }
  const int bnb = (tid & 7) | ((tid >> 7) << 6);
  const int bc = (tid >> 3) & 15;

  f32x4 acc0[4][4], acc1[4][4];
  const f32x4 zz = {0.f, 0.f, 0.f, 0.f};
#pragma unroll
  for (int i = 0; i < 4; ++i)
#pragma unroll
    for (int j = 0; j < 4; ++j) { acc0[i][j] = zz; acc1[i][j] = zz; }

  const float* W0e = W0 + (size_t)e * HID * INTER + n0;
  const float* W1e = W1 + (size_t)e * HID * INTER + n0;

  for (int k0 = 0; k0 < HID; k0 += 64) {
#pragma unroll
    for (int j = 0; j < 8; ++j) {
      int c = j * 256 + tid;
      int m = c >> 4, ch = c & 15;
      float4 v = make_float4(0.f, 0.f, 0.f, 0.f);
      int tok = atok[j];
      if (tok >= 0) v = *(const float4*)(X + (size_t)tok * HID + k0 + 4 * ch);
      uint2 p;
      p.x = f2bf(v.x) | (f2bf(v.y) << 16);
      p.y = f2bf(v.z) | (f2bf(v.w) << 16);
      *(uint2*)(As + swz(m, 8 * ch)) = p;
    }
#pragma unroll
    for (int j = 0; j < 8; ++j) {
      int n = bnb | (j << 3);
      const float* p0 = W0e + (size_t)(k0 + 4 * bc) * INTER + n;
      float a0 = p0[0], a1 = p0[INTER], a2 = p0[2 * INTER], a3 = p0[3 * INTER];
      uint2 q;
      q.x = f2bf(a0) | (f2bf(a1) << 16);
      q.y = f2bf(a2) | (f2bf(a3) << 16);
      *(uint2*)(B0s + swz(n, 8 * bc)) = q;
      const float* p1 = W1e + (size_t)(k0 + 4 * bc) * INTER + n;
      a0 = p1[0]; a1 = p1[INTER]; a2 = p1[2 * INTER]; a3 = p1[3 * INTER];
      q.x = f2bf(a0) | (f2bf(a1) << 16);
      q.y = f2bf(a2) | (f2bf(a3) << 16);
      *(uint2*)(B1s + swz(n, 8 * bc)) = q;
    }
    __syncthreads();
#pragma unroll
    for (int kq = 0; kq < 2; ++kq) {
      int kb = kq * 64 + 16 * (lane >> 4);
      bf16x8 a[4], b0[4], b1[4];
#pragma unroll
      for (int f = 0; f < 4; ++f) {
        int m = wr * 64 + f * 16 + (lane & 15);
        a[f] = *(const bf16x8*)(As + swz(m, kb));
        int n = wc * 64 + f * 16 + (lane & 15);
        b0[f] = *(const bf16x8*)(B0s + swz(n, kb));
        b1[f] = *(const bf16x8*)(B1s + swz(n, kb));
      }
#pragma unroll
      for (int mf = 0; mf < 4; ++mf)
#pragma unroll
        for (int nf = 0; nf < 4; ++nf) {
          acc0[mf][nf] = __builtin_amdgcn_mfma_f32_16x16x32_bf16(a[mf], b0[nf], acc0[mf][nf], 0, 0, 0);
          acc1[mf][nf] = __builtin_amdgcn_mfma_f32_16x16x32_bf16(a[mf], b1[nf], acc1[mf][nf], 0, 0, 0);
        }
    }
    __syncthreads();
  }
#pragma unroll
  for (int mf = 0; mf < 4; ++mf) {
#pragma unroll
    for (int r = 0; r < 4; ++r) {
      int m = wr * 64 + mf * 16 + (lane >> 4) * 4 + r;
      if (m >= mcnt) continue;
      size_t rowbase = (size_t)(row0 + m) * INTER + n0 + wc * 64 + (lane & 15);
#pragma unroll
      for (int nf = 0; nf < 4; ++nf) {
        float h0 = acc0[mf][nf][r];
        float h1 = acc1[mf][nf][r];
        float s = h0 / (1.f + __expf(-h0));
        act[rowbase + nf * 16] = (unsigned short)f2bf(s * h1);
      }
    }
  }
}

__global__ __launch_bounds__(256, 2)
void k_gemm2_fb(const unsigned short* __restrict__ act, const float* __restrict__ WO,
                const int* __restrict__ ntiles, const int* __restrict__ te2,
                const int* __restrict__ tr02, const int* __restrict__ tcnt2,
                const int* __restrict__ rows, const float* __restrict__ rw,
                float* __restrict__ out) {
  const int ty = blockIdx.y;
  if (ty >= ntiles[1]) return;
  const int e = te2[ty], row0 = tr02[ty], mcnt = tcnt2[ty];
  const int n0 = blockIdx.x * BN;
  const int tid = threadIdx.x;
  const int lane = tid & 63, wv = tid >> 6;
  const int wr = wv >> 1, wc = wv & 1;

  __shared__ unsigned char smf[32768];
  unsigned char* As = smf;
  unsigned char* Bs = smf + 16384;

  const int bnb = (tid & 7) | ((tid >> 7) << 6);
  const int bc = (tid >> 3) & 15;

  f32x4 acc[4][4];
  const f32x4 zz = {0.f, 0.f, 0.f, 0.f};
#pragma unroll
  for (int i = 0; i < 4; ++i)
#pragma unroll
    for (int j = 0; j < 4; ++j) acc[i][j] = zz;

  const float* We = WO + (size_t)e * INTER * HID + n0;

  for (int k0 = 0; k0 < INTER; k0 += 64) {
#pragma unroll
    for (int j = 0; j < 4; ++j) {
      int u = j * 256 + tid;
      int m = u >> 3, ch = u & 7;
      uint4 v = make_uint4(0u, 0u, 0u, 0u);
      if (m < mcnt)
        v = *(const uint4*)(act + (size_t)(row0 + m) * INTER + k0 + 8 * ch);
      *(uint4*)(As + swz(m, 16 * ch)) = v;
    }
#pragma unroll
    for (int j = 0; j < 8; ++j) {
      int n = bnb | (j << 3);
      const float* p = We + (size_t)(k0 + 4 * bc) * HID + n;
      float a0 = p[0], a1 = p[HID], a2 = p[2 * HID], a3 = p[3 * HID];
      uint2 q;
      q.x = f2bf(a0) | (f2bf(a1) << 16);
      q.y = f2bf(a2) | (f2bf(a3) << 16);
      *(uint2*)(Bs + swz(n, 8 * bc)) = q;
    }
    __syncthreads();
#pragma unroll
    for (int kq = 0; kq < 2; ++kq) {
      int kb = kq * 64 + 16 * (lane >> 4);
      bf16x8 a[4], b[4];
#pragma unroll
      for (int f = 0; f < 4; ++f) {
        int m = wr * 64 + f * 16 + (lane & 15);
        a[f] = *(const bf16x8*)(As + swz(m, kb));
        int n = wc * 64 + f * 16 + (lane & 15);
        b[f] = *(const bf16x8*)(Bs + swz(n, kb));
      }
#pragma unroll
      for (int mf = 0; mf < 4; ++mf)
#pragma unroll
        for (int nf = 0; nf < 4; ++nf)
          acc[mf][nf] = __builtin_amdgcn_mfma_f32_16x16x32_bf16(a[mf], b[nf], acc[mf][nf], 0, 0, 0);
    }
    __syncthreads();
  }
#pragma unroll
  for (int mf = 0; mf < 4; ++mf) {
#pragma unroll
    for (int r = 0; r < 4; ++r) {
      int m = wr * 64 + mf * 16 + (lane >> 4) * 4 + r;
      if (m >= mcnt) continue;
      int tok = rows[row0 + m];
      float w = rw[row0 + m];
      float* op = out + (size_t)tok * HID + n0 + wc * 64 + (lane & 15);
#pragma unroll
      for (int nf = 0; nf < 4; ++nf)
        atomicAdd(op + nf * 16, w * acc[mf][nf][r]);
    }
  }
}

extern "C" void kernel_launch(void* const* d_in, const int* in_sizes, int n_in,
                              void* d_out, int out_size, void* d_ws, size_t ws_size,
                              hipStream_t stream) {
  const float* X  = (const float*)d_in[0];
  const float* RL = (const float*)d_in[1];
  const float* W0 = (const float*)d_in[2];
  const float* W1 = (const float*)d_in[3];
  const float* WOp = (const float*)d_in[4];
  float* out = (float*)d_out;

  char* ws = (char*)d_ws;
  int* ntiles  = (int*)(ws + 128);
  int* te2     = (int*)(ws + 2048);
  int* tr02    = (int*)(ws + 2560);
  int* tcnt2   = (int*)(ws + 3072);
  float* pw    = (float*)(ws + 8192 + 32768);
  int* rows    = (int*)(ws + 8192 + 65536);
  float* rw    = (float*)(ws + 8192 + 98304);
  int* slotOf  = (int*)(ws + 8192 + 131072);

  const bool big = ws_size >= ((size_t)145 << 20);

  if (big) {
    unsigned short* Xb  = (unsigned short*)(ws + ((size_t)1 << 20));   // 8 MB  [1,9)
    unsigned short* act = (unsigned short*)(ws + ((size_t)16 << 20));  // 32 MB [16,48)
    unsigned short* WT0 = (unsigned short*)(ws + ((size_t)48 << 20));  // 32 MB [48,80)
    unsigned short* WT1 = (unsigned short*)(ws + ((size_t)80 << 20));  // 32 MB [80,112)
    unsigned short* WTo = (unsigned short*)(ws + ((size_t)112 << 20)); // 32 MB [112,144)
    // y (16 MB) reuses WT0's region — WT0 is dead after gemm1; stream order
    // serializes gemm1 -> gemm2. (Must NOT alias Xb/act: rounds 4-7 race.)
    unsigned short* y   = (unsigned short*)(ws + ((size_t)48 << 20));  // [48,64)

    // prep + routing in one launch (block 0 = routing)
    k_prep1r<<<5121, 256, 0, stream>>>(X, Xb, W0, W1, WT0, WT1,
                                       RL, ntiles, te2, tr02, tcnt2,
                                       pw, rows, rw, slotOf);

    // gemm1 + WO-prep fused, interleaved rows: ty<144 even=gemm odd=WO,
    // ty in [144,200) = remaining WO chunks.
    k_gemm1w<<<dim3(INTER / BN, 200), 512, 0, stream>>>(
        Xb, WT0, WT1, WOp, WTo, ntiles, te2, tr02, tcnt2, rows, act);
    k_gemm2n<<<dim3(HID / BN, MAXT), 256, 0, stream>>>(act, WTo, ntiles, te2, tr02, tcnt2, y);
    k_combine<<<(T_TOKENS * HID / 8) / 256, 256, 0, stream>>>(y, pw, slotOf, out);
  } else {
    unsigned short* act = (unsigned short*)(ws + ((size_t)1 << 20));
    hipMemsetAsync(d_out, 0, (size_t)out_size * sizeof(float), stream);
    k_routing<<<1, 1024, 0, stream>>>(RL, ntiles, te2, tr02, tcnt2, pw, rows, rw, slotOf);
    k_gemm1_fb<<<dim3(INTER / BN, MAXT), 256, 0, stream>>>(X, W0, W1, ntiles, te2, tr02, tcnt2, rows, act);
    k_gemm2_fb<<<dim3(HID / BN, MAXT), 256, 0, stream>>>(act, WOp, ntiles, te2, tr02, tcnt2, rows, rw, out);
  }
}

// Round 15
// 212.429 us; speedup vs baseline: 1.1165x; 1.1165x over previous
//
#include <hip/hip_runtime.h>
#include <hip/hip_bf16.h>

#define T_TOKENS 4096
#define HID 1024
#define INTER 2048
#define NEXP 8
#define TOPK 2
#define RTOT (T_TOKENS * TOPK) /* 8192 */
#define BMT 128
#define BN 128
#define MAXT (RTOT / BMT + NEXP) /* 72 */

typedef __attribute__((ext_vector_type(8))) short bf16x8;
typedef __attribute__((ext_vector_type(4))) float f32x4;

typedef __attribute__((address_space(1))) const unsigned int gu32;
typedef __attribute__((address_space(3))) unsigned int lu32;

__device__ __forceinline__ void gl16(const void* g, void* l) {
  __builtin_amdgcn_global_load_lds((gu32*)g, (lu32*)l, 16, 0, 0);
}

__device__ __forceinline__ unsigned f2bf(float f) {
  union { float f; unsigned u; } v; v.f = f;
  unsigned u = v.u;
  return (u + 0x7FFFu + ((u >> 16) & 1u)) >> 16;
}

// packed RNE f32x2 -> bf16x2 (single instruction; src0 -> low half)
__device__ __forceinline__ unsigned cvtpk(float lo, float hi) {
  unsigned r;
  asm("v_cvt_pk_bf16_f32 %0, %1, %2" : "=v"(r) : "v"(lo), "v"(hi));
  return r;
}

__device__ __forceinline__ float bf2f(unsigned short s) {
  union { unsigned u; float f; } v; v.u = ((unsigned)s) << 16;
  return v.f;
}

// old-style swizzle for the fallback kernels ([row][64bf16], 128B rows)
__device__ __forceinline__ int swz(int row, int kb) {
  return row * 128 + (kb ^ ((row & 7) << 4));
}

__device__ __forceinline__ void phase_barrier() {
  asm volatile("" ::: "memory");
  __builtin_amdgcn_s_barrier();
  asm volatile("" ::: "memory");
}

// prep LDS swizzle key: bank-conflict-free column reads (2-way max).
__device__ __forceinline__ int psig(int kap) { return kap ^ ((kap & 1) << 2); }

// ---- routing for fallback path (standalone) ----
__global__ __launch_bounds__(1024)
void k_routing(const float* __restrict__ logits, int* ntiles,
               int* te2, int* tr02, int* tcnt2,
               float* pw, int* rows, float* rw, int* slotOf) {
  __shared__ int cnt[NEXP];
  __shared__ int cur[NEXP];
  const int tid = threadIdx.x;
  if (tid < NEXP) cnt[tid] = 0;
  __syncthreads();
#pragma unroll
  for (int j = 0; j < 4; ++j) {
    int t = j * 1024 + tid;
    float l[NEXP];
#pragma unroll
    for (int i = 0; i < NEXP; ++i) l[i] = logits[t * NEXP + i];
    int i0 = 0; float b0 = l[0];
#pragma unroll
    for (int i = 1; i < NEXP; ++i) if (l[i] > b0) { b0 = l[i]; i0 = i; }
    int i1 = -1; float b1 = -1e30f;
#pragma unroll
    for (int i = 0; i < NEXP; ++i) if (i != i0 && l[i] > b1) { b1 = l[i]; i1 = i; }
    float e = __expf(b1 - b0);
    float w0 = 1.f / (1.f + e);
    float w1 = e / (1.f + e);
    pw[2 * t] = w0; pw[2 * t + 1] = w1;
#pragma unroll
    for (int ex = 0; ex < NEXP; ++ex) {
      int c = __popcll(__ballot(i0 == ex)) + __popcll(__ballot(i1 == ex));
      if ((tid & 63) == 0 && c) atomicAdd(&cnt[ex], c);
    }
  }
  __syncthreads();
  if (tid == 0) {
    int off = 0, nm = 0;
    for (int e = 0; e < NEXP; ++e) {
      int c = cnt[e];
      cur[e] = off;
      for (int m0 = 0; m0 < c; m0 += BMT) {
        te2[nm] = e; tr02[nm] = off + m0; tcnt2[nm] = min(BMT, c - m0); ++nm;
      }
      off += c;
    }
    ntiles[1] = nm;
  }
  __syncthreads();
#pragma unroll
  for (int j = 0; j < 4; ++j) {
    int t = j * 1024 + tid;
    float l[NEXP];
#pragma unroll
    for (int i = 0; i < NEXP; ++i) l[i] = logits[t * NEXP + i];
    int i0 = 0; float b0 = l[0];
#pragma unroll
    for (int i = 1; i < NEXP; ++i) if (l[i] > b0) { b0 = l[i]; i0 = i; }
    int i1 = -1; float b1 = -1e30f;
#pragma unroll
    for (int i = 0; i < NEXP; ++i) if (i != i0 && l[i] > b1) { b1 = l[i]; i1 = i; }
    float e = __expf(b1 - b0);
    float ww[2] = {1.f / (1.f + e), e / (1.f + e)};
    int ee[2] = {i0, i1};
#pragma unroll
    for (int k = 0; k < TOPK; ++k) {
      int s = atomicAdd(&cur[ee[k]], 1);
      rows[s] = t;
      rw[s] = ww[k];
      slotOf[2 * t + k] = s;
    }
  }
}

// ---- prepass + routing, ONE launch (5121 blocks x 256 thr):
//  block 0:            routing (top2 + tile list + scatter)
//  blocks [1,1025):    X f32 -> bf16
//  blocks [1025,5121): W0/W1 f32 -> bf16 tiles [E][16][16][128n][32k]
__global__ __launch_bounds__(256)
void k_prep1r(const float* __restrict__ X, unsigned short* __restrict__ Xb,
              const float* __restrict__ W0, const float* __restrict__ W1,
              unsigned short* __restrict__ T0, unsigned short* __restrict__ T1,
              const float* __restrict__ logits, int* ntiles,
              int* te2, int* tr02, int* tcnt2,
              float* pw, int* rows, float* rw, int* slotOf) {
  int bid = blockIdx.x;
  const int tid = threadIdx.x;

  if (bid == 0) {
    // ---- routing: 256 threads x 16 tokens ----
    __shared__ int cnt[NEXP];
    __shared__ int cur[NEXP];
    if (tid < NEXP) cnt[tid] = 0;
    __syncthreads();
#pragma unroll
    for (int j = 0; j < 16; ++j) {
      int t = j * 256 + tid;
      float l[NEXP];
#pragma unroll
      for (int i = 0; i < NEXP; ++i) l[i] = logits[t * NEXP + i];
      int i0 = 0; float b0 = l[0];
#pragma unroll
      for (int i = 1; i < NEXP; ++i) if (l[i] > b0) { b0 = l[i]; i0 = i; }
      int i1 = -1; float b1 = -1e30f;
#pragma unroll
      for (int i = 0; i < NEXP; ++i) if (i != i0 && l[i] > b1) { b1 = l[i]; i1 = i; }
      float e = __expf(b1 - b0);
      float w0 = 1.f / (1.f + e);
      pw[2 * t] = w0; pw[2 * t + 1] = 1.f - w0;
#pragma unroll
      for (int ex = 0; ex < NEXP; ++ex) {
        int c = __popcll(__ballot(i0 == ex)) + __popcll(__ballot(i1 == ex));
        if ((tid & 63) == 0 && c) atomicAdd(&cnt[ex], c);
      }
    }
    __syncthreads();
    if (tid == 0) {
      int off = 0, nm = 0;
      for (int e = 0; e < NEXP; ++e) {
        int c = cnt[e];
        cur[e] = off;
        for (int m0 = 0; m0 < c; m0 += BMT) {
          te2[nm] = e; tr02[nm] = off + m0; tcnt2[nm] = min(BMT, c - m0); ++nm;
        }
        off += c;
      }
      ntiles[1] = nm;
    }
    __syncthreads();
    // scatter pass (recompute top2 -> low VGPR)
#pragma unroll
    for (int j = 0; j < 16; ++j) {
      int t = j * 256 + tid;
      float l[NEXP];
#pragma unroll
      for (int i = 0; i < NEXP; ++i) l[i] = logits[t * NEXP + i];
      int i0 = 0; float b0 = l[0];
#pragma unroll
      for (int i = 1; i < NEXP; ++i) if (l[i] > b0) { b0 = l[i]; i0 = i; }
      int i1 = -1; float b1 = -1e30f;
#pragma unroll
      for (int i = 0; i < NEXP; ++i) if (i != i0 && l[i] > b1) { b1 = l[i]; i1 = i; }
      float e = __expf(b1 - b0);
      float ww0 = 1.f / (1.f + e);
      int ee[2] = {i0, i1};
      float ww[2] = {ww0, 1.f - ww0};
#pragma unroll
      for (int k = 0; k < TOPK; ++k) {
        int s = atomicAdd(&cur[ee[k]], 1);
        rows[s] = t;
        rw[s] = ww[k];
        slotOf[2 * t + k] = s;
      }
    }
    return;
  }

  if (bid < 1025) {
    int base = (bid - 1) * 1024 + tid;
#pragma unroll
    for (int j = 0; j < 4; ++j) {
      int i = base + j * 256;
      float4 v = *(const float4*)(X + (size_t)i * 4);
      uint2 p;
      p.x = cvtpk(v.x, v.y);
      p.y = cvtpk(v.z, v.w);
      *(uint2*)(Xb + (size_t)i * 4) = p;
    }
    return;
  }
  bid -= 1025;
  const int w = bid >> 11;     // 0:W0 1:W1
  const int r = bid & 2047;
  const float* W = (w == 0) ? W0 : W1;
  unsigned short* T = (w == 0) ? T0 : T1;
  // nt fastest: 16 consecutive blocks cover full 2048-col row stripes
  const int nt = r & 15, kt = (r >> 4) & 15, e = r >> 8;
  __shared__ float ls[64 * 128];  // 32KB, conflict-free swizzle (psig)
  const float* src = W + (size_t)e * HID * INTER + (size_t)(kt * 64) * INTER + nt * 128;
#pragma unroll
  for (int t = 0; t < 8; ++t) {
    int u = t * 256 + tid;
    int k = u >> 5, n4 = u & 31;
    float4 v = *(const float4*)(src + (size_t)k * INTER + n4 * 4);
    *(float4*)(ls + k * 128 + ((n4 ^ psig(k >> 3)) << 2)) = v;
  }
  __syncthreads();
  unsigned short* dst = T + (((size_t)e * 16 + nt) * 16 + kt) * 8192;
#pragma unroll
  for (int t = 0; t < 4; ++t) {
    int v = t * 256 + tid;                       // uint4 index in output tile
    int kt2 = v >> 9, n = (v >> 2) & 127, sw = v & 3;
    int kc = kt2 * 4 + (sw ^ ((n >> 1) & 3));    // logical 8-k chunk
    const float* col = ls + (size_t)(kc * 8) * 128 +
                       (((n >> 2) ^ psig(kc)) << 2) + (n & 3);
    uint4 q;
    q.x = cvtpk(col[0 * 128], col[1 * 128]);
    q.y = cvtpk(col[2 * 128], col[3 * 128]);
    q.z = cvtpk(col[4 * 128], col[5 * 128]);
    q.w = cvtpk(col[6 * 128], col[7 * 128]);
    *(uint4*)(dst + (size_t)v * 8) = q;
  }
}

// ======== GEMM1 + WO-prep merged launch (WO appended after gemm rows) ========
// ty < MAXT: act = silu(X@W0) * (X@W1)  (8 waves, 128x128 dual-B, BK=32)
// ty >= MAXT: tile WO into WTo (fills scheduler as gemm blocks retire)
__global__ __launch_bounds__(512, 4)
void k_gemm1w(const unsigned short* __restrict__ Xb,
              const unsigned short* __restrict__ WT0,
              const unsigned short* __restrict__ WT1,
              const float* __restrict__ WO,
              unsigned short* __restrict__ WTo,
              const int* __restrict__ ntiles, const int* __restrict__ te2,
              const int* __restrict__ tr02, const int* __restrict__ tcnt2,
              const int* __restrict__ rows,
              unsigned short* __restrict__ act) {
  const int ty = blockIdx.y;
  const int nt = blockIdx.x;
  const int tid = threadIdx.x;
  __shared__ __align__(16) unsigned char sm[49152];

  if (ty >= MAXT) {
    // ---- WO prep block: [E][8][32][128n][32k] tiled bf16, nt-fastest ----
    const int r = (ty - MAXT) * 16 + nt;   // 0..2047
    const int ntt = r & 7, kt = (r >> 3) & 31, e = r >> 8;
    float* ls = (float*)sm;  // 32KB
    const float* src = WO + (size_t)e * INTER * HID + (size_t)(kt * 64) * HID + ntt * 128;
#pragma unroll
    for (int t = 0; t < 4; ++t) {
      int u = t * 512 + tid;               // 0..2047 float4 units
      int k = u >> 5, n4 = u & 31;
      float4 v = *(const float4*)(src + (size_t)k * HID + n4 * 4);
      *(float4*)(ls + k * 128 + ((n4 ^ psig(k >> 3)) << 2)) = v;
    }
    __syncthreads();
    unsigned short* dst = WTo + (((size_t)e * 8 + ntt) * 32 + kt) * 8192;
#pragma unroll
    for (int t = 0; t < 2; ++t) {
      int v = t * 512 + tid;               // 0..1023 uint4 units
      int kt2 = v >> 9, n = (v >> 2) & 127, sw = v & 3;
      int kc = kt2 * 4 + (sw ^ ((n >> 1) & 3));
      const float* col = ls + (size_t)(kc * 8) * 128 +
                         (((n >> 2) ^ psig(kc)) << 2) + (n & 3);
      uint4 q;
      q.x = cvtpk(col[0 * 128], col[1 * 128]);
      q.y = cvtpk(col[2 * 128], col[3 * 128]);
      q.z = cvtpk(col[4 * 128], col[5 * 128]);
      q.w = cvtpk(col[6 * 128], col[7 * 128]);
      *(uint4*)(dst + (size_t)v * 8) = q;
    }
    return;
  }

  if (ty >= ntiles[1]) return;
  const int e = te2[ty], row0 = tr02[ty], mcnt = tcnt2[ty];
  const int n0 = nt * BN;
  const int lane = tid & 63, wv = tid >> 6;
  const int mh = wv >> 2, nq = wv & 3;  // wave out: 64m x 32n per B
  const int l15 = lane & 15, sl = lane >> 4;

  const int am = tid >> 2;
  const int atok = rows[row0 + (am < mcnt ? am : mcnt - 1)];
  const int askc = ((tid & 3) ^ ((tid >> 3) & 3)) * 8;  // shorts
  const unsigned short* B0t = WT0 + ((size_t)e * 16 + nt) * 32 * 4096;
  const unsigned short* B1t = WT1 + ((size_t)e * 16 + nt) * 32 * 4096;

  int aoff[4], boff[2];
#pragma unroll
  for (int f = 0; f < 4; ++f) {
    int m = mh * 64 + f * 16 + l15;
    aoff[f] = m * 64 + ((sl ^ ((m >> 1) & 3)) << 4);
  }
#pragma unroll
  for (int g = 0; g < 2; ++g) {
    int n = nq * 32 + g * 16 + l15;
    boff[g] = n * 64 + ((sl ^ ((n >> 1) & 3)) << 4);
  }

  f32x4 acc0[4][2], acc1[4][2];
  const f32x4 zz = {0.f, 0.f, 0.f, 0.f};
#pragma unroll
  for (int f = 0; f < 4; ++f)
#pragma unroll
    for (int g = 0; g < 2; ++g) { acc0[f][g] = zz; acc1[f][g] = zz; }

  const int NT_K = HID / 32;  // 32

  gl16(Xb + (size_t)atok * HID + askc, sm + tid * 16);
  gl16(B0t + (size_t)tid * 8, sm + 8192 + tid * 16);
  gl16(B1t + (size_t)tid * 8, sm + 16384 + tid * 16);

  for (int t = 0; t < NT_K; ++t) {
    unsigned char* cur = sm + (t & 1) * 24576;
    unsigned char* nxt = sm + ((t + 1) & 1) * 24576;
    const int tn = (t + 1 < NT_K) ? (t + 1) : (NT_K - 1);

    gl16(Xb + (size_t)atok * HID + tn * 32 + askc, nxt + tid * 16);
    gl16(B0t + (size_t)tn * 4096 + tid * 8, nxt + 8192 + tid * 16);
    gl16(B1t + (size_t)tn * 4096 + tid * 8, nxt + 16384 + tid * 16);
    asm volatile("s_waitcnt vmcnt(3)" ::: "memory");
    __builtin_amdgcn_sched_barrier(0);
    phase_barrier();

    bf16x8 aA[4], b0q[2], b1q[2];
#pragma unroll
    for (int g = 0; g < 2; ++g) {
      b0q[g] = *(const bf16x8*)(cur + 8192 + boff[g]);
      b1q[g] = *(const bf16x8*)(cur + 16384 + boff[g]);
    }
#pragma unroll
    for (int f = 0; f < 4; ++f) aA[f] = *(const bf16x8*)(cur + aoff[f]);
    __builtin_amdgcn_s_setprio(1);
#pragma unroll
    for (int f = 0; f < 4; ++f)
#pragma unroll
      for (int g = 0; g < 2; ++g) {
        acc0[f][g] = __builtin_amdgcn_mfma_f32_16x16x32_bf16(aA[f], b0q[g], acc0[f][g], 0, 0, 0);
        acc1[f][g] = __builtin_amdgcn_mfma_f32_16x16x32_bf16(aA[f], b1q[g], acc1[f][g], 0, 0, 0);
      }
    __builtin_amdgcn_s_setprio(0);
    phase_barrier();
  }

#pragma unroll
  for (int f = 0; f < 4; ++f) {
#pragma unroll
    for (int r = 0; r < 4; ++r) {
      int m = mh * 64 + f * 16 + sl * 4 + r;
      if (m >= mcnt) continue;
      size_t base = (size_t)(row0 + m) * INTER + n0 + nq * 32 + l15;
#pragma unroll
      for (int g = 0; g < 2; ++g) {
        float h0 = acc0[f][g][r];
        float h1 = acc1[f][g][r];
        float s = h0 / (1.f + __expf(-h0));
        act[base + g * 16] = (unsigned short)f2bf(s * h1);
      }
    }
  }
}

// ======== GEMM2: 128x128, 4 waves, BK=32, dbuf 32KB ========
// y[slot] = act@WO (bf16, unweighted)
__global__ __launch_bounds__(256, 4)
void k_gemm2n(const unsigned short* __restrict__ act,
              const unsigned short* __restrict__ WTo,
              const int* __restrict__ ntiles, const int* __restrict__ te2,
              const int* __restrict__ tr02, const int* __restrict__ tcnt2,
              unsigned short* __restrict__ y) {
  const int ty = blockIdx.y;
  if (ty >= ntiles[1]) return;
  const int e = te2[ty], row0 = tr02[ty], mcnt = tcnt2[ty];
  const int nt = blockIdx.x, n0 = nt * BN;
  const int tid = threadIdx.x, lane = tid & 63, wv = tid >> 6;
  const int wr = wv >> 1, wc = wv & 1;  // wave out 64x64
  const int l15 = lane & 15, sl = lane >> 4;

  // 2 x (A 8KB | B 8KB)
  __shared__ __align__(16) unsigned char sm[32768];

  const int am0 = tid >> 2, am1 = 64 + (tid >> 2);
  const int ar0 = row0 + (am0 < mcnt ? am0 : mcnt - 1);
  const int ar1 = row0 + (am1 < mcnt ? am1 : mcnt - 1);
  const int askc = ((tid & 3) ^ ((tid >> 3) & 3)) * 8;
  const unsigned short* Bt = WTo + ((size_t)e * 8 + nt) * 64 * 4096;

  int aoff[4], boff[4];
#pragma unroll
  for (int f = 0; f < 4; ++f) {
    int m = wr * 64 + f * 16 + l15;
    aoff[f] = m * 64 + ((sl ^ ((m >> 1) & 3)) << 4);
    int n = wc * 64 + f * 16 + l15;
    boff[f] = n * 64 + ((sl ^ ((n >> 1) & 3)) << 4);
  }

  f32x4 acc[4][4];
  const f32x4 zz = {0.f, 0.f, 0.f, 0.f};
#pragma unroll
  for (int i = 0; i < 4; ++i)
#pragma unroll
    for (int j = 0; j < 4; ++j) acc[i][j] = zz;

  const int NT_K = INTER / 32;  // 64

  gl16(act + (size_t)ar0 * INTER + askc, sm + tid * 16);
  gl16(act + (size_t)ar1 * INTER + askc, sm + (256 + tid) * 16);
  gl16(Bt + (size_t)tid * 8, sm + 8192 + tid * 16);
  gl16(Bt + (size_t)(256 + tid) * 8, sm + 8192 + (256 + tid) * 16);

  for (int t = 0; t < NT_K; ++t) {
    unsigned char* cur = sm + (t & 1) * 16384;
    unsigned char* nxt = sm + ((t + 1) & 1) * 16384;
    const int tn = (t + 1 < NT_K) ? (t + 1) : (NT_K - 1);

    gl16(act + (size_t)ar0 * INTER + tn * 32 + askc, nxt + tid * 16);
    gl16(act + (size_t)ar1 * INTER + tn * 32 + askc, nxt + (256 + tid) * 16);
    gl16(Bt + (size_t)tn * 4096 + tid * 8, nxt + 8192 + tid * 16);
    gl16(Bt + ((size_t)tn * 4096 + 2048) + tid * 8, nxt + 8192 + (256 + tid) * 16);
    asm volatile("s_waitcnt vmcnt(4)" ::: "memory");
    __builtin_amdgcn_sched_barrier(0);
    phase_barrier();

    bf16x8 af[4], bb[4];
#pragma unroll
    for (int f = 0; f < 4; ++f) {
      af[f] = *(const bf16x8*)(cur + aoff[f]);
      bb[f] = *(const bf16x8*)(cur + 8192 + boff[f]);
    }
    __builtin_amdgcn_s_setprio(1);
#pragma unroll
    for (int mf = 0; mf < 4; ++mf)
#pragma unroll
      for (int nf = 0; nf < 4; ++nf)
        acc[mf][nf] = __builtin_amdgcn_mfma_f32_16x16x32_bf16(af[mf], bb[nf], acc[mf][nf], 0, 0, 0);
    __builtin_amdgcn_s_setprio(0);
    phase_barrier();
  }

#pragma unroll
  for (int mf = 0; mf < 4; ++mf) {
#pragma unroll
    for (int r = 0; r < 4; ++r) {
      int m = wr * 64 + mf * 16 + sl * 4 + r;
      if (m >= mcnt) continue;
      unsigned short* yp = y + (size_t)(row0 + m) * HID + n0 + wc * 64 + l15;
#pragma unroll
      for (int nf = 0; nf < 4; ++nf)
        yp[nf * 16] = (unsigned short)f2bf(acc[mf][nf][r]);
    }
  }
}

// ---------------- combine: out[t] = w0*y[s0] + w1*y[s1] ----------------
__global__ void k_combine(const unsigned short* __restrict__ y,
                          const float* __restrict__ pw,
                          const int* __restrict__ slotOf,
                          float* __restrict__ out) {
  int idx = blockIdx.x * blockDim.x + threadIdx.x;
  int t = idx >> 7, hc = (idx & 127) * 8;
  int s0 = slotOf[2 * t], s1 = slotOf[2 * t + 1];
  float w0 = pw[2 * t], w1 = pw[2 * t + 1];
  uint4 a = *(const uint4*)(y + (size_t)s0 * HID + hc);
  uint4 b = *(const uint4*)(y + (size_t)s1 * HID + hc);
  float o[8];
  const unsigned* ap = (const unsigned*)&a;
  const unsigned* bp = (const unsigned*)&b;
#pragma unroll
  for (int i = 0; i < 4; ++i) {
    o[2 * i]     = w0 * bf2f((unsigned short)(ap[i] & 0xFFFF)) + w1 * bf2f((unsigned short)(bp[i] & 0xFFFF));
    o[2 * i + 1] = w0 * bf2f((unsigned short)(ap[i] >> 16))    + w1 * bf2f((unsigned short)(bp[i] >> 16));
  }
  float* op = out + (size_t)t * HID + hc;
  *(float4*)op = make_float4(o[0], o[1], o[2], o[3]);
  *(float4*)(op + 4) = make_float4(o[4], o[5], o[6], o[7]);
}

// ================= fallback (f32-direct, 128-tiles) if ws too small =================
__global__ __launch_bounds__(256, 2)
void k_gemm1_fb(const float* __restrict__ X, const float* __restrict__ W0,
                const float* __restrict__ W1, const int* __restrict__ ntiles,
                const int* __restrict__ te2, const int* __restrict__ tr02,
                const int* __restrict__ tcnt2, const int* __restrict__ rows,
                unsigned short* __restrict__ act) {
  const int ty = blockIdx.y;
  if (ty >= ntiles[1]) return;
  const int e = te2[ty], row0 = tr02[ty], mcnt = tcnt2[ty];
  const int n0 = blockIdx.x * BN;
  const int tid = threadIdx.x;
  const int lane = tid & 63, wv = tid >> 6;
  const int wr = wv >> 1, wc = wv & 1;

  __shared__ unsigned char smf[49152];
  unsigned char* As = smf;
  unsigned char* B0s = smf + 16384;
  unsigned char* B1s = smf + 32768;

  int atok[8];
#pragma unroll
  for (int j = 0; j < 8; ++j) {
    int m = (j * 256 + tid) >> 4;
    atok[j] = (m < mcnt) ? rows[row0 + m] : -1;
  }
  const int bnb = (tid & 7) | ((tid >> 7) << 6);
  const int bc = (tid >> 3) & 15;

  f32x4 acc0[4][4], acc1[4][4];
  const f32x4 zz = {0.f, 0.f, 0.f, 0.f};
#pragma unroll
  for (int i = 0; i < 4; ++i)
#pragma unroll
    for (int j = 0; j < 4; ++j) { acc0[i][j] = zz; acc1[i][j] = zz; }

  const float* W0e = W0 + (size_t)e * HID * INTER + n0;
  const float* W1e = W1 + (size_t)e * HID * INTER + n0;

  for (int k0 = 0; k0 < HID; k0 += 64) {
#pragma unroll
    for (int j = 0; j < 8; ++j) {
      int c = j * 256 + tid;
      int m = c >> 4, ch = c & 15;
      float4 v = make_float4(0.f, 0.f, 0.f, 0.f);
      int tok = atok[j];
      if (tok >= 0) v = *(const float4*)(X + (size_t)tok * HID + k0 + 4 * ch);
      uint2 p;
      p.x = f2bf(v.x) | (f2bf(v.y) << 16);
      p.y = f2bf(v.z) | (f2bf(v.w) << 16);
      *(uint2*)(As + swz(m, 8 * ch)) = p;
    }
#pragma unroll
    for (int j = 0; j < 8; ++j) {
      int n = bnb | (j << 3);
      const float* p0 = W0e + (size_t)(k0 + 4 * bc) * INTER + n;
      float a0 = p0[0], a1 = p0[INTER], a2 = p0[2 * INTER], a3 = p0[3 * INTER];
      uint2 q;
      q.x = f2bf(a0) | (f2bf(a1) << 16);
      q.y = f2bf(a2) | (f2bf(a3) << 16);
      *(uint2*)(B0s + swz(n, 8 * bc)) = q;
      const float* p1 = W1e + (size_t)(k0 + 4 * bc) * INTER + n;
      a0 = p1[0]; a1 = p1[INTER]; a2 = p1[2 * INTER]; a3 = p1[3 * INTER];
      q.x = f2bf(a0) | (f2bf(a1) << 16);
      q.y = f2bf(a2) | (f2bf(a3) << 16);
      *(uint2*)(B1s + swz(n, 8 * bc)) = q;
    }
    __syncthreads();
#pragma unroll
    for (int kq = 0; kq < 2; ++kq) {
      int kb = kq * 64 + 16 * (lane >> 4);
      bf16x8 a[4], b0[4], b1[4];
#pragma unroll
      for (int f = 0; f < 4; ++f) {
        int m = wr * 64 + f * 16 + (lane & 15);
        a[f] = *(const bf16x8*)(As + swz(m, kb));
        int n = wc * 64 + f * 16 + (lane & 15);
        b0[f] = *(const bf16x8*)(B0s + swz(n, kb));
        b1[f] = *(const bf16x8*)(B1s + swz(n, kb));
      }
#pragma unroll
      for (int mf = 0; mf < 4; ++mf)
#pragma unroll
        for (int nf = 0; nf < 4; ++nf) {
          acc0[mf][nf] = __builtin_amdgcn_mfma_f32_16x16x32_bf16(a[mf], b0[nf], acc0[mf][nf], 0, 0, 0);
          acc1[mf][nf] = __builtin_amdgcn_mfma_f32_16x16x32_bf16(a[mf], b1[nf], acc1[mf][nf], 0, 0, 0);
        }
    }
    __syncthreads();
  }
#pragma unroll
  for (int mf = 0; mf < 4; ++mf) {
#pragma unroll
    for (int r = 0; r < 4; ++r) {
      int m = wr * 64 + mf * 16 + (lane >> 4) * 4 + r;
      if (m >= mcnt) continue;
      size_t rowbase = (size_t)(row0 + m) * INTER + n0 + wc * 64 + (lane & 15);
#pragma unroll
      for (int nf = 0; nf < 4; ++nf) {
        float h0 = acc0[mf][nf][r];
        float h1 = acc1[mf][nf][r];
        float s = h0 / (1.f + __expf(-h0));
        act[rowbase + nf * 16] = (unsigned short)f2bf(s * h1);
      }
    }
  }
}

__global__ __launch_bounds__(256, 2)
void k_gemm2_fb(const unsigned short* __restrict__ act, const float* __restrict__ WO,
                const int* __restrict__ ntiles, const int* __restrict__ te2,
                const int* __restrict__ tr02, const int* __restrict__ tcnt2,
                const int* __restrict__ rows, const float* __restrict__ rw,
                float* __restrict__ out) {
  const int ty = blockIdx.y;
  if (ty >= ntiles[1]) return;
  const int e = te2[ty], row0 = tr02[ty], mcnt = tcnt2[ty];
  const int n0 = blockIdx.x * BN;
  const int tid = threadIdx.x;
  const int lane = tid & 63, wv = tid >> 6;
  const int wr = wv >> 1, wc = wv & 1;

  __shared__ unsigned char smf[32768];
  unsigned char* As = smf;
  unsigned char* Bs = smf + 16384;

  const int bnb = (tid & 7) | ((tid >> 7) << 6);
  const int bc = (tid >> 3) & 15;

  f32x4 acc[4][4];
  const f32x4 zz = {0.f, 0.f, 0.f, 0.f};
#pragma unroll
  for (int i = 0; i < 4; ++i)
#pragma unroll
    for (int j = 0; j < 4; ++j) acc[i][j] = zz;

  const float* We = WO + (size_t)e * INTER * HID + n0;

  for (int k0 = 0; k0 < INTER; k0 += 64) {
#pragma unroll
    for (int j = 0; j < 4; ++j) {
      int u = j * 256 + tid;
      int m = u >> 3, ch = u & 7;
      uint4 v = make_uint4(0u, 0u, 0u, 0u);
      if (m < mcnt)
        v = *(const uint4*)(act + (size_t)(row0 + m) * INTER + k0 + 8 * ch);
      *(uint4*)(As + swz(m, 16 * ch)) = v;
    }
#pragma unroll
    for (int j = 0; j < 8; ++j) {
      int n = bnb | (j << 3);
      const float* p = We + (size_t)(k0 + 4 * bc) * HID + n;
      float a0 = p[0], a1 = p[HID], a2 = p[2 * HID], a3 = p[3 * HID];
      uint2 q;
      q.x = f2bf(a0) | (f2bf(a1) << 16);
      q.y = f2bf(a2) | (f2bf(a3) << 16);
      *(uint2*)(Bs + swz(n, 8 * bc)) = q;
    }
    __syncthreads();
#pragma unroll
    for (int kq = 0; kq < 2; ++kq) {
      int kb = kq * 64 + 16 * (lane >> 4);
      bf16x8 a[4], b[4];
#pragma unroll
      for (int f = 0; f < 4; ++f) {
        int m = wr * 64 + f * 16 + (lane & 15);
        a[f] = *(const bf16x8*)(As + swz(m, kb));
        int n = wc * 64 + f * 16 + (lane & 15);
        b[f] = *(const bf16x8*)(Bs + swz(n, kb));
      }
#pragma unroll
      for (int mf = 0; mf < 4; ++mf)
#pragma unroll
        for (int nf = 0; nf < 4; ++nf)
          acc[mf][nf] = __builtin_amdgcn_mfma_f32_16x16x32_bf16(a[mf], b[nf], acc[mf][nf], 0, 0, 0);
    }
    __syncthreads();
  }
#pragma unroll
  for (int mf = 0; mf < 4; ++mf) {
#pragma unroll
    for (int r = 0; r < 4; ++r) {
      int m = wr * 64 + mf * 16 + (lane >> 4) * 4 + r;
      if (m >= mcnt) continue;
      int tok = rows[row0 + m];
      float w = rw[row0 + m];
      float* op = out + (size_t)tok * HID + n0 + wc * 64 + (lane & 15);
#pragma unroll
      for (int nf = 0; nf < 4; ++nf)
        atomicAdd(op + nf * 16, w * acc[mf][nf][r]);
    }
  }
}

extern "C" void kernel_launch(void* const* d_in, const int* in_sizes, int n_in,
                              void* d_out, int out_size, void* d_ws, size_t ws_size,
                              hipStream_t stream) {
  const float* X  = (const float*)d_in[0];
  const float* RL = (const float*)d_in[1];
  const float* W0 = (const float*)d_in[2];
  const float* W1 = (const float*)d_in[3];
  const float* WOp = (const float*)d_in[4];
  float* out = (float*)d_out;

  char* ws = (char*)d_ws;
  int* ntiles  = (int*)(ws + 128);
  int* te2     = (int*)(ws + 2048);
  int* tr02    = (int*)(ws + 2560);
  int* tcnt2   = (int*)(ws + 3072);
  float* pw    = (float*)(ws + 8192 + 32768);
  int* rows    = (int*)(ws + 8192 + 65536);
  float* rw    = (float*)(ws + 8192 + 98304);
  int* slotOf  = (int*)(ws + 8192 + 131072);

  const bool big = ws_size >= ((size_t)145 << 20);

  if (big) {
    unsigned short* Xb  = (unsigned short*)(ws + ((size_t)1 << 20));   // 8 MB  [1,9)
    unsigned short* act = (unsigned short*)(ws + ((size_t)16 << 20));  // 32 MB [16,48)
    unsigned short* WT0 = (unsigned short*)(ws + ((size_t)48 << 20));  // 32 MB [48,80)
    unsigned short* WT1 = (unsigned short*)(ws + ((size_t)80 << 20));  // 32 MB [80,112)
    unsigned short* WTo = (unsigned short*)(ws + ((size_t)112 << 20)); // 32 MB [112,144)
    // y (16 MB) reuses WT0's region — WT0 is dead after gemm1; stream order
    // serializes gemm1 -> gemm2. (Must NOT alias Xb/act: rounds 4-7 race.)
    unsigned short* y   = (unsigned short*)(ws + ((size_t)48 << 20));  // [48,64)

    // prep + routing in one launch (block 0 = routing)
    k_prep1r<<<5121, 256, 0, stream>>>(X, Xb, W0, W1, WT0, WT1,
                                       RL, ntiles, te2, tr02, tcnt2,
                                       pw, rows, rw, slotOf);

    // gemm1 + WO-prep fused launch: ty in [0,MAXT) = gemm rows,
    // ty in [MAXT, MAXT+128) = 2048 WO tiling blocks (16 per row).
    k_gemm1w<<<dim3(INTER / BN, MAXT + 128), 512, 0, stream>>>(
        Xb, WT0, WT1, WOp, WTo, ntiles, te2, tr02, tcnt2, rows, act);
    k_gemm2n<<<dim3(HID / BN, MAXT), 256, 0, stream>>>(act, WTo, ntiles, te2, tr02, tcnt2, y);
    k_combine<<<(T_TOKENS * HID / 8) / 256, 256, 0, stream>>>(y, pw, slotOf, out);
  } else {
    unsigned short* act = (unsigned short*)(ws + ((size_t)1 << 20));
    hipMemsetAsync(d_out, 0, (size_t)out_size * sizeof(float), stream);
    k_routing<<<1, 1024, 0, stream>>>(RL, ntiles, te2, tr02, tcnt2, pw, rows, rw, slotOf);
    k_gemm1_fb<<<dim3(INTER / BN, MAXT), 256, 0, stream>>>(X, W0, W1, ntiles, te2, tr02, tcnt2, rows, act);
    k_gemm2_fb<<<dim3(HID / BN, MAXT), 256, 0, stream>>>(act, WOp, ntiles, te2, tr02, tcnt2, rows, rw, out);
  }
}

// Round 16
// 209.858 us; speedup vs baseline: 1.1302x; 1.0123x over previous
//
#include <hip/hip_runtime.h>
#include <hip/hip_bf16.h>

#define T_TOKENS 4096
#define HID 1024
#define INTER 2048
#define NEXP 8
#define TOPK 2
#define RTOT (T_TOKENS * TOPK) /* 8192 */
#define BMT 128
#define BN 128
#define MAXT (RTOT / BMT + NEXP) /* 72 */

typedef __attribute__((ext_vector_type(8))) short bf16x8;
typedef __attribute__((ext_vector_type(4))) float f32x4;

typedef __attribute__((address_space(1))) const unsigned int gu32;
typedef __attribute__((address_space(3))) unsigned int lu32;

__device__ __forceinline__ void gl16(const void* g, void* l) {
  __builtin_amdgcn_global_load_lds((gu32*)g, (lu32*)l, 16, 0, 0);
}

__device__ __forceinline__ unsigned f2bf(float f) {
  union { float f; unsigned u; } v; v.f = f;
  unsigned u = v.u;
  return (u + 0x7FFFu + ((u >> 16) & 1u)) >> 16;
}

// packed RNE f32x2 -> bf16x2 (single instruction; src0 -> low half)
__device__ __forceinline__ unsigned cvtpk(float lo, float hi) {
  unsigned r;
  asm("v_cvt_pk_bf16_f32 %0, %1, %2" : "=v"(r) : "v"(lo), "v"(hi));
  return r;
}

__device__ __forceinline__ float bf2f(unsigned short s) {
  union { unsigned u; float f; } v; v.u = ((unsigned)s) << 16;
  return v.f;
}

// old-style swizzle for the fallback kernels ([row][64bf16], 128B rows)
__device__ __forceinline__ int swz(int row, int kb) {
  return row * 128 + (kb ^ ((row & 7) << 4));
}

__device__ __forceinline__ void phase_barrier() {
  asm volatile("" ::: "memory");
  __builtin_amdgcn_s_barrier();
  asm volatile("" ::: "memory");
}

// prep LDS swizzle key: bank-conflict-free column reads (2-way max).
__device__ __forceinline__ int psig(int kap) { return kap ^ ((kap & 1) << 2); }

// ---- routing for fallback path (standalone) ----
__global__ __launch_bounds__(1024)
void k_routing(const float* __restrict__ logits, int* ntiles,
               int* te2, int* tr02, int* tcnt2,
               float* pw, int* rows, float* rw, int* slotOf) {
  __shared__ int cnt[NEXP];
  __shared__ int cur[NEXP];
  const int tid = threadIdx.x;
  if (tid < NEXP) cnt[tid] = 0;
  __syncthreads();
#pragma unroll
  for (int j = 0; j < 4; ++j) {
    int t = j * 1024 + tid;
    float l[NEXP];
#pragma unroll
    for (int i = 0; i < NEXP; ++i) l[i] = logits[t * NEXP + i];
    int i0 = 0; float b0 = l[0];
#pragma unroll
    for (int i = 1; i < NEXP; ++i) if (l[i] > b0) { b0 = l[i]; i0 = i; }
    int i1 = -1; float b1 = -1e30f;
#pragma unroll
    for (int i = 0; i < NEXP; ++i) if (i != i0 && l[i] > b1) { b1 = l[i]; i1 = i; }
    float e = __expf(b1 - b0);
    float w0 = 1.f / (1.f + e);
    float w1 = e / (1.f + e);
    pw[2 * t] = w0; pw[2 * t + 1] = w1;
#pragma unroll
    for (int ex = 0; ex < NEXP; ++ex) {
      int c = __popcll(__ballot(i0 == ex)) + __popcll(__ballot(i1 == ex));
      if ((tid & 63) == 0 && c) atomicAdd(&cnt[ex], c);
    }
  }
  __syncthreads();
  if (tid == 0) {
    int off = 0, nm = 0;
    for (int e = 0; e < NEXP; ++e) {
      int c = cnt[e];
      cur[e] = off;
      for (int m0 = 0; m0 < c; m0 += BMT) {
        te2[nm] = e; tr02[nm] = off + m0; tcnt2[nm] = min(BMT, c - m0); ++nm;
      }
      off += c;
    }
    ntiles[1] = nm;
  }
  __syncthreads();
#pragma unroll
  for (int j = 0; j < 4; ++j) {
    int t = j * 1024 + tid;
    float l[NEXP];
#pragma unroll
    for (int i = 0; i < NEXP; ++i) l[i] = logits[t * NEXP + i];
    int i0 = 0; float b0 = l[0];
#pragma unroll
    for (int i = 1; i < NEXP; ++i) if (l[i] > b0) { b0 = l[i]; i0 = i; }
    int i1 = -1; float b1 = -1e30f;
#pragma unroll
    for (int i = 0; i < NEXP; ++i) if (i != i0 && l[i] > b1) { b1 = l[i]; i1 = i; }
    float e = __expf(b1 - b0);
    float ww[2] = {1.f / (1.f + e), e / (1.f + e)};
    int ee[2] = {i0, i1};
#pragma unroll
    for (int k = 0; k < TOPK; ++k) {
      int s = atomicAdd(&cur[ee[k]], 1);
      rows[s] = t;
      rw[s] = ww[k];
      slotOf[2 * t + k] = s;
    }
  }
}

// ---- prepass + routing, ONE launch (9217 blocks x 256 thr):
//  block 0:            routing (top2 + tile list + scatter)
//  blocks [1,1025):    X f32 -> bf16
//  blocks [1025,9217): W0/W1 f32 -> bf16 tiles, 32-k granularity (16KB LDS
//                      -> ~8 blocks/CU co-resident for latency hiding).
//                      Output chunk = contiguous 4096 shorts at
//                      ((e*16+nt)*32 + kt32)*4096.
__global__ __launch_bounds__(256)
void k_prep1r(const float* __restrict__ X, unsigned short* __restrict__ Xb,
              const float* __restrict__ W0, const float* __restrict__ W1,
              unsigned short* __restrict__ T0, unsigned short* __restrict__ T1,
              const float* __restrict__ logits, int* ntiles,
              int* te2, int* tr02, int* tcnt2,
              float* pw, int* rows, float* rw, int* slotOf) {
  int bid = blockIdx.x;
  const int tid = threadIdx.x;

  if (bid == 0) {
    // ---- routing: 256 threads x 16 tokens ----
    __shared__ int cnt[NEXP];
    __shared__ int cur[NEXP];
    if (tid < NEXP) cnt[tid] = 0;
    __syncthreads();
#pragma unroll
    for (int j = 0; j < 16; ++j) {
      int t = j * 256 + tid;
      float l[NEXP];
#pragma unroll
      for (int i = 0; i < NEXP; ++i) l[i] = logits[t * NEXP + i];
      int i0 = 0; float b0 = l[0];
#pragma unroll
      for (int i = 1; i < NEXP; ++i) if (l[i] > b0) { b0 = l[i]; i0 = i; }
      int i1 = -1; float b1 = -1e30f;
#pragma unroll
      for (int i = 0; i < NEXP; ++i) if (i != i0 && l[i] > b1) { b1 = l[i]; i1 = i; }
      float e = __expf(b1 - b0);
      float w0 = 1.f / (1.f + e);
      pw[2 * t] = w0; pw[2 * t + 1] = 1.f - w0;
#pragma unroll
      for (int ex = 0; ex < NEXP; ++ex) {
        int c = __popcll(__ballot(i0 == ex)) + __popcll(__ballot(i1 == ex));
        if ((tid & 63) == 0 && c) atomicAdd(&cnt[ex], c);
      }
    }
    __syncthreads();
    if (tid == 0) {
      int off = 0, nm = 0;
      for (int e = 0; e < NEXP; ++e) {
        int c = cnt[e];
        cur[e] = off;
        for (int m0 = 0; m0 < c; m0 += BMT) {
          te2[nm] = e; tr02[nm] = off + m0; tcnt2[nm] = min(BMT, c - m0); ++nm;
        }
        off += c;
      }
      ntiles[1] = nm;
    }
    __syncthreads();
    // scatter pass (recompute top2 -> low VGPR)
#pragma unroll
    for (int j = 0; j < 16; ++j) {
      int t = j * 256 + tid;
      float l[NEXP];
#pragma unroll
      for (int i = 0; i < NEXP; ++i) l[i] = logits[t * NEXP + i];
      int i0 = 0; float b0 = l[0];
#pragma unroll
      for (int i = 1; i < NEXP; ++i) if (l[i] > b0) { b0 = l[i]; i0 = i; }
      int i1 = -1; float b1 = -1e30f;
#pragma unroll
      for (int i = 0; i < NEXP; ++i) if (i != i0 && l[i] > b1) { b1 = l[i]; i1 = i; }
      float e = __expf(b1 - b0);
      float ww0 = 1.f / (1.f + e);
      int ee[2] = {i0, i1};
      float ww[2] = {ww0, 1.f - ww0};
#pragma unroll
      for (int k = 0; k < TOPK; ++k) {
        int s = atomicAdd(&cur[ee[k]], 1);
        rows[s] = t;
        rw[s] = ww[k];
        slotOf[2 * t + k] = s;
      }
    }
    return;
  }

  if (bid < 1025) {
    int base = (bid - 1) * 1024 + tid;
#pragma unroll
    for (int j = 0; j < 4; ++j) {
      int i = base + j * 256;
      float4 v = *(const float4*)(X + (size_t)i * 4);
      uint2 p;
      p.x = cvtpk(v.x, v.y);
      p.y = cvtpk(v.z, v.w);
      *(uint2*)(Xb + (size_t)i * 4) = p;
    }
    return;
  }
  bid -= 1025;
  const int w = bid >> 12;     // 0:W0 1:W1 (4096 blocks each)
  const int r = bid & 4095;
  const float* W = (w == 0) ? W0 : W1;
  unsigned short* T = (w == 0) ? T0 : T1;
  // nt fastest within a k-stripe: blocks covering one 32-row stripe are adjacent
  const int nt = r & 15, kt32 = (r >> 4) & 31, e = r >> 9;
  __shared__ float ls[32 * 128];  // 16KB, conflict-free swizzle (psig)
  const float* src = W + (size_t)e * HID * INTER + (size_t)(kt32 * 32) * INTER + nt * 128;
#pragma unroll
  for (int t = 0; t < 4; ++t) {
    int u = t * 256 + tid;
    int k = u >> 5, n4 = u & 31;     // k in [0,32)
    float4 v = *(const float4*)(src + (size_t)k * INTER + n4 * 4);
    *(float4*)(ls + k * 128 + ((n4 ^ psig(k >> 3)) << 2)) = v;
  }
  __syncthreads();
  unsigned short* dst = T + (((size_t)e * 16 + nt) * 32 + kt32) * 4096;
#pragma unroll
  for (int t = 0; t < 2; ++t) {
    int v = t * 256 + tid;           // uint4 index in the 4096-short chunk
    int n = v >> 2, sw = v & 3;
    int kc = sw ^ ((n >> 1) & 3);    // logical 8-k chunk, [0,4)
    const float* col = ls + (size_t)(kc * 8) * 128 +
                       (((n >> 2) ^ psig(kc)) << 2) + (n & 3);
    uint4 q;
    q.x = cvtpk(col[0 * 128], col[1 * 128]);
    q.y = cvtpk(col[2 * 128], col[3 * 128]);
    q.z = cvtpk(col[4 * 128], col[5 * 128]);
    q.w = cvtpk(col[6 * 128], col[7 * 128]);
    *(uint4*)(dst + (size_t)v * 8) = q;
  }
}

// ======== GEMM1 + WO-prep merged launch (WO appended after gemm rows) ========
// ty < MAXT: act = silu(X@W0) * (X@W1)  (8 waves, 128x128 dual-B, BK=32)
// ty >= MAXT: tile WO into WTo (fills scheduler as gemm blocks retire)
__global__ __launch_bounds__(512, 4)
void k_gemm1w(const unsigned short* __restrict__ Xb,
              const unsigned short* __restrict__ WT0,
              const unsigned short* __restrict__ WT1,
              const float* __restrict__ WO,
              unsigned short* __restrict__ WTo,
              const int* __restrict__ ntiles, const int* __restrict__ te2,
              const int* __restrict__ tr02, const int* __restrict__ tcnt2,
              const int* __restrict__ rows,
              unsigned short* __restrict__ act) {
  const int ty = blockIdx.y;
  const int nt = blockIdx.x;
  const int tid = threadIdx.x;
  __shared__ __align__(16) unsigned char sm[49152];

  if (ty >= MAXT) {
    // ---- WO prep block: [E][8][32][128n][32k] tiled bf16, nt-fastest ----
    const int r = (ty - MAXT) * 16 + nt;   // 0..2047
    const int ntt = r & 7, kt = (r >> 3) & 31, e = r >> 8;
    float* ls = (float*)sm;  // 32KB
    const float* src = WO + (size_t)e * INTER * HID + (size_t)(kt * 64) * HID + ntt * 128;
#pragma unroll
    for (int t = 0; t < 4; ++t) {
      int u = t * 512 + tid;               // 0..2047 float4 units
      int k = u >> 5, n4 = u & 31;
      float4 v = *(const float4*)(src + (size_t)k * HID + n4 * 4);
      *(float4*)(ls + k * 128 + ((n4 ^ psig(k >> 3)) << 2)) = v;
    }
    __syncthreads();
    unsigned short* dst = WTo + (((size_t)e * 8 + ntt) * 32 + kt) * 8192;
#pragma unroll
    for (int t = 0; t < 2; ++t) {
      int v = t * 512 + tid;               // 0..1023 uint4 units
      int kt2 = v >> 9, n = (v >> 2) & 127, sw = v & 3;
      int kc = kt2 * 4 + (sw ^ ((n >> 1) & 3));
      const float* col = ls + (size_t)(kc * 8) * 128 +
                         (((n >> 2) ^ psig(kc)) << 2) + (n & 3);
      uint4 q;
      q.x = cvtpk(col[0 * 128], col[1 * 128]);
      q.y = cvtpk(col[2 * 128], col[3 * 128]);
      q.z = cvtpk(col[4 * 128], col[5 * 128]);
      q.w = cvtpk(col[6 * 128], col[7 * 128]);
      *(uint4*)(dst + (size_t)v * 8) = q;
    }
    return;
  }

  if (ty >= ntiles[1]) return;
  const int e = te2[ty], row0 = tr02[ty], mcnt = tcnt2[ty];
  const int n0 = nt * BN;
  const int lane = tid & 63, wv = tid >> 6;
  const int mh = wv >> 2, nq = wv & 3;  // wave out: 64m x 32n per B
  const int l15 = lane & 15, sl = lane >> 4;

  const int am = tid >> 2;
  const int atok = rows[row0 + (am < mcnt ? am : mcnt - 1)];
  const int askc = ((tid & 3) ^ ((tid >> 3) & 3)) * 8;  // shorts
  const unsigned short* B0t = WT0 + ((size_t)e * 16 + nt) * 32 * 4096;
  const unsigned short* B1t = WT1 + ((size_t)e * 16 + nt) * 32 * 4096;

  int aoff[4], boff[2];
#pragma unroll
  for (int f = 0; f < 4; ++f) {
    int m = mh * 64 + f * 16 + l15;
    aoff[f] = m * 64 + ((sl ^ ((m >> 1) & 3)) << 4);
  }
#pragma unroll
  for (int g = 0; g < 2; ++g) {
    int n = nq * 32 + g * 16 + l15;
    boff[g] = n * 64 + ((sl ^ ((n >> 1) & 3)) << 4);
  }

  f32x4 acc0[4][2], acc1[4][2];
  const f32x4 zz = {0.f, 0.f, 0.f, 0.f};
#pragma unroll
  for (int f = 0; f < 4; ++f)
#pragma unroll
    for (int g = 0; g < 2; ++g) { acc0[f][g] = zz; acc1[f][g] = zz; }

  const int NT_K = HID / 32;  // 32

  gl16(Xb + (size_t)atok * HID + askc, sm + tid * 16);
  gl16(B0t + (size_t)tid * 8, sm + 8192 + tid * 16);
  gl16(B1t + (size_t)tid * 8, sm + 16384 + tid * 16);

  for (int t = 0; t < NT_K; ++t) {
    unsigned char* cur = sm + (t & 1) * 24576;
    unsigned char* nxt = sm + ((t + 1) & 1) * 24576;
    const int tn = (t + 1 < NT_K) ? (t + 1) : (NT_K - 1);

    gl16(Xb + (size_t)atok * HID + tn * 32 + askc, nxt + tid * 16);
    gl16(B0t + (size_t)tn * 4096 + tid * 8, nxt + 8192 + tid * 16);
    gl16(B1t + (size_t)tn * 4096 + tid * 8, nxt + 16384 + tid * 16);
    asm volatile("s_waitcnt vmcnt(3)" ::: "memory");
    __builtin_amdgcn_sched_barrier(0);
    phase_barrier();

    bf16x8 aA[4], b0q[2], b1q[2];
#pragma unroll
    for (int g = 0; g < 2; ++g) {
      b0q[g] = *(const bf16x8*)(cur + 8192 + boff[g]);
      b1q[g] = *(const bf16x8*)(cur + 16384 + boff[g]);
    }
#pragma unroll
    for (int f = 0; f < 4; ++f) aA[f] = *(const bf16x8*)(cur + aoff[f]);
    __builtin_amdgcn_s_setprio(1);
#pragma unroll
    for (int f = 0; f < 4; ++f)
#pragma unroll
      for (int g = 0; g < 2; ++g) {
        acc0[f][g] = __builtin_amdgcn_mfma_f32_16x16x32_bf16(aA[f], b0q[g], acc0[f][g], 0, 0, 0);
        acc1[f][g] = __builtin_amdgcn_mfma_f32_16x16x32_bf16(aA[f], b1q[g], acc1[f][g], 0, 0, 0);
      }
    __builtin_amdgcn_s_setprio(0);
    phase_barrier();
  }

#pragma unroll
  for (int f = 0; f < 4; ++f) {
#pragma unroll
    for (int r = 0; r < 4; ++r) {
      int m = mh * 64 + f * 16 + sl * 4 + r;
      if (m >= mcnt) continue;
      size_t base = (size_t)(row0 + m) * INTER + n0 + nq * 32 + l15;
#pragma unroll
      for (int g = 0; g < 2; ++g) {
        float h0 = acc0[f][g][r];
        float h1 = acc1[f][g][r];
        float s = h0 / (1.f + __expf(-h0));
        act[base + g * 16] = (unsigned short)f2bf(s * h1);
      }
    }
  }
}

// ======== GEMM2: 128x128, 4 waves, BK=32, dbuf 32KB ========
// y[slot] = act@WO (bf16, unweighted)
__global__ __launch_bounds__(256, 4)
void k_gemm2n(const unsigned short* __restrict__ act,
              const unsigned short* __restrict__ WTo,
              const int* __restrict__ ntiles, const int* __restrict__ te2,
              const int* __restrict__ tr02, const int* __restrict__ tcnt2,
              unsigned short* __restrict__ y) {
  const int ty = blockIdx.y;
  if (ty >= ntiles[1]) return;
  const int e = te2[ty], row0 = tr02[ty], mcnt = tcnt2[ty];
  const int nt = blockIdx.x, n0 = nt * BN;
  const int tid = threadIdx.x, lane = tid & 63, wv = tid >> 6;
  const int wr = wv >> 1, wc = wv & 1;  // wave out 64x64
  const int l15 = lane & 15, sl = lane >> 4;

  // 2 x (A 8KB | B 8KB)
  __shared__ __align__(16) unsigned char sm[32768];

  const int am0 = tid >> 2, am1 = 64 + (tid >> 2);
  const int ar0 = row0 + (am0 < mcnt ? am0 : mcnt - 1);
  const int ar1 = row0 + (am1 < mcnt ? am1 : mcnt - 1);
  const int askc = ((tid & 3) ^ ((tid >> 3) & 3)) * 8;
  const unsigned short* Bt = WTo + ((size_t)e * 8 + nt) * 64 * 4096;

  int aoff[4], boff[4];
#pragma unroll
  for (int f = 0; f < 4; ++f) {
    int m = wr * 64 + f * 16 + l15;
    aoff[f] = m * 64 + ((sl ^ ((m >> 1) & 3)) << 4);
    int n = wc * 64 + f * 16 + l15;
    boff[f] = n * 64 + ((sl ^ ((n >> 1) & 3)) << 4);
  }

  f32x4 acc[4][4];
  const f32x4 zz = {0.f, 0.f, 0.f, 0.f};
#pragma unroll
  for (int i = 0; i < 4; ++i)
#pragma unroll
    for (int j = 0; j < 4; ++j) acc[i][j] = zz;

  const int NT_K = INTER / 32;  // 64

  gl16(act + (size_t)ar0 * INTER + askc, sm + tid * 16);
  gl16(act + (size_t)ar1 * INTER + askc, sm + (256 + tid) * 16);
  gl16(Bt + (size_t)tid * 8, sm + 8192 + tid * 16);
  gl16(Bt + (size_t)(256 + tid) * 8, sm + 8192 + (256 + tid) * 16);

  for (int t = 0; t < NT_K; ++t) {
    unsigned char* cur = sm + (t & 1) * 16384;
    unsigned char* nxt = sm + ((t + 1) & 1) * 16384;
    const int tn = (t + 1 < NT_K) ? (t + 1) : (NT_K - 1);

    gl16(act + (size_t)ar0 * INTER + tn * 32 + askc, nxt + tid * 16);
    gl16(act + (size_t)ar1 * INTER + tn * 32 + askc, nxt + (256 + tid) * 16);
    gl16(Bt + (size_t)tn * 4096 + tid * 8, nxt + 8192 + tid * 16);
    gl16(Bt + ((size_t)tn * 4096 + 2048) + tid * 8, nxt + 8192 + (256 + tid) * 16);
    asm volatile("s_waitcnt vmcnt(4)" ::: "memory");
    __builtin_amdgcn_sched_barrier(0);
    phase_barrier();

    bf16x8 af[4], bb[4];
#pragma unroll
    for (int f = 0; f < 4; ++f) {
      af[f] = *(const bf16x8*)(cur + aoff[f]);
      bb[f] = *(const bf16x8*)(cur + 8192 + boff[f]);
    }
    __builtin_amdgcn_s_setprio(1);
#pragma unroll
    for (int mf = 0; mf < 4; ++mf)
#pragma unroll
      for (int nf = 0; nf < 4; ++nf)
        acc[mf][nf] = __builtin_amdgcn_mfma_f32_16x16x32_bf16(af[mf], bb[nf], acc[mf][nf], 0, 0, 0);
    __builtin_amdgcn_s_setprio(0);
    phase_barrier();
  }

#pragma unroll
  for (int mf = 0; mf < 4; ++mf) {
#pragma unroll
    for (int r = 0; r < 4; ++r) {
      int m = wr * 64 + mf * 16 + sl * 4 + r;
      if (m >= mcnt) continue;
      unsigned short* yp = y + (size_t)(row0 + m) * HID + n0 + wc * 64 + l15;
#pragma unroll
      for (int nf = 0; nf < 4; ++nf)
        yp[nf * 16] = (unsigned short)f2bf(acc[mf][nf][r]);
    }
  }
}

// ---------------- combine: out[t] = w0*y[s0] + w1*y[s1] ----------------
__global__ void k_combine(const unsigned short* __restrict__ y,
                          const float* __restrict__ pw,
                          const int* __restrict__ slotOf,
                          float* __restrict__ out) {
  int idx = blockIdx.x * blockDim.x + threadIdx.x;
  int t = idx >> 7, hc = (idx & 127) * 8;
  int s0 = slotOf[2 * t], s1 = slotOf[2 * t + 1];
  float w0 = pw[2 * t], w1 = pw[2 * t + 1];
  uint4 a = *(const uint4*)(y + (size_t)s0 * HID + hc);
  uint4 b = *(const uint4*)(y + (size_t)s1 * HID + hc);
  float o[8];
  const unsigned* ap = (const unsigned*)&a;
  const unsigned* bp = (const unsigned*)&b;
#pragma unroll
  for (int i = 0; i < 4; ++i) {
    o[2 * i]     = w0 * bf2f((unsigned short)(ap[i] & 0xFFFF)) + w1 * bf2f((unsigned short)(bp[i] & 0xFFFF));
    o[2 * i + 1] = w0 * bf2f((unsigned short)(ap[i] >> 16))    + w1 * bf2f((unsigned short)(bp[i] >> 16));
  }
  float* op = out + (size_t)t * HID + hc;
  *(float4*)op = make_float4(o[0], o[1], o[2], o[3]);
  *(float4*)(op + 4) = make_float4(o[4], o[5], o[6], o[7]);
}

// ================= fallback (f32-direct, 128-tiles) if ws too small =================
__global__ __launch_bounds__(256, 2)
void k_gemm1_fb(const float* __restrict__ X, const float* __restrict__ W0,
                const float* __restrict__ W1, const int* __restrict__ ntiles,
                const int* __restrict__ te2, const int* __restrict__ tr02,
                const int* __restrict__ tcnt2, const int* __restrict__ rows,
                unsigned short* __restrict__ act) {
  const int ty = blockIdx.y;
  if (ty >= ntiles[1]) return;
  const int e = te2[ty], row0 = tr02[ty], mcnt = tcnt2[ty];
  const int n0 = blockIdx.x * BN;
  const int tid = threadIdx.x;
  const int lane = tid & 63, wv = tid >> 6;
  const int wr = wv >> 1, wc = wv & 1;

  __shared__ unsigned char smf[49152];
  unsigned char* As = smf;
  unsigned char* B0s = smf + 16384;
  unsigned char* B1s = smf + 32768;

  int atok[8];
#pragma unroll
  for (int j = 0; j < 8; ++j) {
    int m = (j * 256 + tid) >> 4;
    atok[j] = (m < mcnt) ? rows[row0 + m] : -1;
  }
  const int bnb = (tid & 7) | ((tid >> 7) << 6);
  const int bc = (tid >> 3) & 15;

  f32x4 acc0[4][4], acc1[4][4];
  const f32x4 zz = {0.f, 0.f, 0.f, 0.f};
#pragma unroll
  for (int i = 0; i < 4; ++i)
#pragma unroll
    for (int j = 0; j < 4; ++j) { acc0[i][j] = zz; acc1[i][j] = zz; }

  const float* W0e = W0 + (size_t)e * HID * INTER + n0;
  const float* W1e = W1 + (size_t)e * HID * INTER + n0;

  for (int k0 = 0; k0 < HID; k0 += 64) {
#pragma unroll
    for (int j = 0; j < 8; ++j) {
      int c = j * 256 + tid;
      int m = c >> 4, ch = c & 15;
      float4 v = make_float4(0.f, 0.f, 0.f, 0.f);
      int tok = atok[j];
      if (tok >= 0) v = *(const float4*)(X + (size_t)tok * HID + k0 + 4 * ch);
      uint2 p;
      p.x = f2bf(v.x) | (f2bf(v.y) << 16);
      p.y = f2bf(v.z) | (f2bf(v.w) << 16);
      *(uint2*)(As + swz(m, 8 * ch)) = p;
    }
#pragma unroll
    for (int j = 0; j < 8; ++j) {
      int n = bnb | (j << 3);
      const float* p0 = W0e + (size_t)(k0 + 4 * bc) * INTER + n;
      float a0 = p0[0], a1 = p0[INTER], a2 = p0[2 * INTER], a3 = p0[3 * INTER];
      uint2 q;
      q.x = f2bf(a0) | (f2bf(a1) << 16);
      q.y = f2bf(a2) | (f2bf(a3) << 16);
      *(uint2*)(B0s + swz(n, 8 * bc)) = q;
      const float* p1 = W1e + (size_t)(k0 + 4 * bc) * INTER + n;
      a0 = p1[0]; a1 = p1[INTER]; a2 = p1[2 * INTER]; a3 = p1[3 * INTER];
      q.x = f2bf(a0) | (f2bf(a1) << 16);
      q.y = f2bf(a2) | (f2bf(a3) << 16);
      *(uint2*)(B1s + swz(n, 8 * bc)) = q;
    }
    __syncthreads();
#pragma unroll
    for (int kq = 0; kq < 2; ++kq) {
      int kb = kq * 64 + 16 * (lane >> 4);
      bf16x8 a[4], b0[4], b1[4];
#pragma unroll
      for (int f = 0; f < 4; ++f) {
        int m = wr * 64 + f * 16 + (lane & 15);
        a[f] = *(const bf16x8*)(As + swz(m, kb));
        int n = wc * 64 + f * 16 + (lane & 15);
        b0[f] = *(const bf16x8*)(B0s + swz(n, kb));
        b1[f] = *(const bf16x8*)(B1s + swz(n, kb));
      }
#pragma unroll
      for (int mf = 0; mf < 4; ++mf)
#pragma unroll
        for (int nf = 0; nf < 4; ++nf) {
          acc0[mf][nf] = __builtin_amdgcn_mfma_f32_16x16x32_bf16(a[mf], b0[nf], acc0[mf][nf], 0, 0, 0);
          acc1[mf][nf] = __builtin_amdgcn_mfma_f32_16x16x32_bf16(a[mf], b1[nf], acc1[mf][nf], 0, 0, 0);
        }
    }
    __syncthreads();
  }
#pragma unroll
  for (int mf = 0; mf < 4; ++mf) {
#pragma unroll
    for (int r = 0; r < 4; ++r) {
      int m = wr * 64 + mf * 16 + (lane >> 4) * 4 + r;
      if (m >= mcnt) continue;
      size_t rowbase = (size_t)(row0 + m) * INTER + n0 + wc * 64 + (lane & 15);
#pragma unroll
      for (int nf = 0; nf < 4; ++nf) {
        float h0 = acc0[mf][nf][r];
        float h1 = acc1[mf][nf][r];
        float s = h0 / (1.f + __expf(-h0));
        act[rowbase + nf * 16] = (unsigned short)f2bf(s * h1);
      }
    }
  }
}

__global__ __launch_bounds__(256, 2)
void k_gemm2_fb(const unsigned short* __restrict__ act, const float* __restrict__ WO,
                const int* __restrict__ ntiles, const int* __restrict__ te2,
                const int* __restrict__ tr02, const int* __restrict__ tcnt2,
                const int* __restrict__ rows, const float* __restrict__ rw,
                float* __restrict__ out) {
  const int ty = blockIdx.y;
  if (ty >= ntiles[1]) return;
  const int e = te2[ty], row0 = tr02[ty], mcnt = tcnt2[ty];
  const int n0 = blockIdx.x * BN;
  const int tid = threadIdx.x;
  const int lane = tid & 63, wv = tid >> 6;
  const int wr = wv >> 1, wc = wv & 1;

  __shared__ unsigned char smf[32768];
  unsigned char* As = smf;
  unsigned char* Bs = smf + 16384;

  const int bnb = (tid & 7) | ((tid >> 7) << 6);
  const int bc = (tid >> 3) & 15;

  f32x4 acc[4][4];
  const f32x4 zz = {0.f, 0.f, 0.f, 0.f};
#pragma unroll
  for (int i = 0; i < 4; ++i)
#pragma unroll
    for (int j = 0; j < 4; ++j) acc[i][j] = zz;

  const float* We = WO + (size_t)e * INTER * HID + n0;

  for (int k0 = 0; k0 < INTER; k0 += 64) {
#pragma unroll
    for (int j = 0; j < 4; ++j) {
      int u = j * 256 + tid;
      int m = u >> 3, ch = u & 7;
      uint4 v = make_uint4(0u, 0u, 0u, 0u);
      if (m < mcnt)
        v = *(const uint4*)(act + (size_t)(row0 + m) * INTER + k0 + 8 * ch);
      *(uint4*)(As + swz(m, 16 * ch)) = v;
    }
#pragma unroll
    for (int j = 0; j < 8; ++j) {
      int n = bnb | (j << 3);
      const float* p = We + (size_t)(k0 + 4 * bc) * HID + n;
      float a0 = p[0], a1 = p[HID], a2 = p[2 * HID], a3 = p[3 * HID];
      uint2 q;
      q.x = f2bf(a0) | (f2bf(a1) << 16);
      q.y = f2bf(a2) | (f2bf(a3) << 16);
      *(uint2*)(Bs + swz(n, 8 * bc)) = q;
    }
    __syncthreads();
#pragma unroll
    for (int kq = 0; kq < 2; ++kq) {
      int kb = kq * 64 + 16 * (lane >> 4);
      bf16x8 a[4], b[4];
#pragma unroll
      for (int f = 0; f < 4; ++f) {
        int m = wr * 64 + f * 16 + (lane & 15);
        a[f] = *(const bf16x8*)(As + swz(m, kb));
        int n = wc * 64 + f * 16 + (lane & 15);
        b[f] = *(const bf16x8*)(Bs + swz(n, kb));
      }
#pragma unroll
      for (int mf = 0; mf < 4; ++mf)
#pragma unroll
        for (int nf = 0; nf < 4; ++nf)
          acc[mf][nf] = __builtin_amdgcn_mfma_f32_16x16x32_bf16(a[mf], b[nf], acc[mf][nf], 0, 0, 0);
    }
    __syncthreads();
  }
#pragma unroll
  for (int mf = 0; mf < 4; ++mf) {
#pragma unroll
    for (int r = 0; r < 4; ++r) {
      int m = wr * 64 + mf * 16 + (lane >> 4) * 4 + r;
      if (m >= mcnt) continue;
      int tok = rows[row0 + m];
      float w = rw[row0 + m];
      float* op = out + (size_t)tok * HID + n0 + wc * 64 + (lane & 15);
#pragma unroll
      for (int nf = 0; nf < 4; ++nf)
        atomicAdd(op + nf * 16, w * acc[mf][nf][r]);
    }
  }
}

extern "C" void kernel_launch(void* const* d_in, const int* in_sizes, int n_in,
                              void* d_out, int out_size, void* d_ws, size_t ws_size,
                              hipStream_t stream) {
  const float* X  = (const float*)d_in[0];
  const float* RL = (const float*)d_in[1];
  const float* W0 = (const float*)d_in[2];
  const float* W1 = (const float*)d_in[3];
  const float* WOp = (const float*)d_in[4];
  float* out = (float*)d_out;

  char* ws = (char*)d_ws;
  int* ntiles  = (int*)(ws + 128);
  int* te2     = (int*)(ws + 2048);
  int* tr02    = (int*)(ws + 2560);
  int* tcnt2   = (int*)(ws + 3072);
  float* pw    = (float*)(ws + 8192 + 32768);
  int* rows    = (int*)(ws + 8192 + 65536);
  float* rw    = (float*)(ws + 8192 + 98304);
  int* slotOf  = (int*)(ws + 8192 + 131072);

  const bool big = ws_size >= ((size_t)145 << 20);

  if (big) {
    unsigned short* Xb  = (unsigned short*)(ws + ((size_t)1 << 20));   // 8 MB  [1,9)
    unsigned short* act = (unsigned short*)(ws + ((size_t)16 << 20));  // 32 MB [16,48)
    unsigned short* WT0 = (unsigned short*)(ws + ((size_t)48 << 20));  // 32 MB [48,80)
    unsigned short* WT1 = (unsigned short*)(ws + ((size_t)80 << 20));  // 32 MB [80,112)
    unsigned short* WTo = (unsigned short*)(ws + ((size_t)112 << 20)); // 32 MB [112,144)
    // y (16 MB) reuses WT0's region — WT0 is dead after gemm1; stream order
    // serializes gemm1 -> gemm2. (Must NOT alias Xb/act: rounds 4-7 race.)
    unsigned short* y   = (unsigned short*)(ws + ((size_t)48 << 20));  // [48,64)

    // prep + routing in one launch (block 0 = routing; W tiles 32-k granular)
    k_prep1r<<<9217, 256, 0, stream>>>(X, Xb, W0, W1, WT0, WT1,
                                       RL, ntiles, te2, tr02, tcnt2,
                                       pw, rows, rw, slotOf);

    // gemm1 + WO-prep fused launch: ty in [0,MAXT) = gemm rows,
    // ty in [MAXT, MAXT+128) = 2048 WO tiling blocks (16 per row).
    k_gemm1w<<<dim3(INTER / BN, MAXT + 128), 512, 0, stream>>>(
        Xb, WT0, WT1, WOp, WTo, ntiles, te2, tr02, tcnt2, rows, act);
    k_gemm2n<<<dim3(HID / BN, MAXT), 256, 0, stream>>>(act, WTo, ntiles, te2, tr02, tcnt2, y);
    k_combine<<<(T_TOKENS * HID / 8) / 256, 256, 0, stream>>>(y, pw, slotOf, out);
  } else {
    unsigned short* act = (unsigned short*)(ws + ((size_t)1 << 20));
    hipMemsetAsync(d_out, 0, (size_t)out_size * sizeof(float), stream);
    k_routing<<<1, 1024, 0, stream>>>(RL, ntiles, te2, tr02, tcnt2, pw, rows, rw, slotOf);
    k_gemm1_fb<<<dim3(INTER / BN, MAXT), 256, 0, stream>>>(X, W0, W1, ntiles, te2, tr02, tcnt2, rows, act);
    k_gemm2_fb<<<dim3(HID / BN, MAXT), 256, 0, stream>>>(act, WOp, ntiles, te2, tr02, tcnt2, rows, rw, out);
  }
}